// Round 6
// baseline (11891.906 us; speedup 1.0000x reference)
//
#include <hip/hip_runtime.h>

typedef unsigned short u16;
typedef float f32x4 __attribute__((ext_vector_type(4)));

__device__ inline float bf2f(u16 b) { return __builtin_bit_cast(float, ((unsigned)b) << 16); }
__device__ inline float h2f(u16 h) { return (float)__builtin_bit_cast(_Float16, h); }
__device__ inline u16 f2h_bits(float f) { return __builtin_bit_cast(u16, (_Float16)f); }

// Input dtype detector: capacities ~ [50,100]. bf16 inputs -> u16[0,2,4,6] are
// in-range bf16 values; fp32 inputs -> those are random low mantissa halves.
__device__ inline int detect_bf16(const void* caps) {
    const u16* c = (const u16*)caps;
    int cnt = 0;
#pragma unroll
    for (int k = 0; k < 4; ++k) {
        float v = bf2f(c[2 * k]);
        if (v >= 20.f && v <= 200.f) cnt++;
    }
    return cnt >= 2;
}
__device__ inline float ldin(const void* p, size_t i, int flag) {
    return flag ? bf2f(((const u16*)p)[i]) : ((const float*)p)[i];
}

// canonical fp32 arena offsets (elements)
#define A_SRCW 0
#define A_SRCB 131584
#define A_CANDW 132096
#define A_CANDB 263680
#define A_DEPW 264192
#define A_DEPB 395776
#define A_FEASW 396288
#define A_FEASB 396800
#define A_PW 396801
#define A_PB 397825
#define A_BO 397827
#define A_B1 400899
#define A_B2 413187
#define A_TOTAL 416259

// ---------------------------------------------------------------------------
// GEMM (VALU fp32 core — known-good path from round 5):
//   acc = scale*(A @ Bt^T) + bias; CF=0: C fp16 (+optional fp32 resid);
//   CF=1: C fp32.
// A: M x K row-major fp16. Bt: N x K row-major fp16. bias fp32.
// Batch offset per blockIdx.z: off = (z>>3)*so + (z&7)*si.
// BM=BN=64, BK=32, 256 threads; each thread computes a 4x4 output block.
// M % 64 == 0; N guarded via B-row clamp + epilogue skip. K % 32 == 0.
// ---------------------------------------------------------------------------
template <int CF>
__global__ __launch_bounds__(256) void gemm_v(
    const u16* __restrict__ A, int lda, long long a_so, long long a_si,
    const u16* __restrict__ B, int ldb, long long b_so, long long b_si,
    void* __restrict__ Cv, int ldc, long long c_so, long long c_si,
    const float* __restrict__ bias, float* __restrict__ resid,
    float scale, int relu, int N, int K)
{
    __shared__ __attribute__((aligned(16))) u16 As[64 * 32];
    __shared__ __attribute__((aligned(16))) u16 Bs[64 * 32];

    const int z = blockIdx.z;
    A += (long long)(z >> 3) * a_so + (long long)(z & 7) * a_si;
    B += (long long)(z >> 3) * b_so + (long long)(z & 7) * b_si;
    const long long coff = (long long)(z >> 3) * c_so + (long long)(z & 7) * c_si;

    const int m0 = blockIdx.y * 64;
    const int n0 = blockIdx.x * 64;
    const int t = threadIdx.x;
    const int tm = t >> 4, tn = t & 15;  // 16x16 thread grid of 4x4 blocks

    float acc[4][4] = {};

    for (int k0 = 0; k0 < K; k0 += 32) {
        __syncthreads();  // protect previous tile
        {
            // stage 64x32 fp16 tiles: 2048 u16 = 256 threads x 8 u16 (16B)
            int row = t >> 2, c8 = (t & 3) * 8;
            *(uint4*)(As + row * 32 + c8) =
                *(const uint4*)(A + (long long)(m0 + row) * lda + k0 + c8);
            int rn = n0 + row;
            if (rn > N - 1) rn = N - 1;  // clamp OOB rows (values unused)
            *(uint4*)(Bs + row * 32 + c8) =
                *(const uint4*)(B + (long long)rn * ldb + k0 + c8);
        }
        __syncthreads();

#pragma unroll 4
        for (int kk = 0; kk < 32; ++kk) {
            float av[4], bv[4];
#pragma unroll
            for (int i = 0; i < 4; ++i) av[i] = h2f(As[(tm * 4 + i) * 32 + kk]);
#pragma unroll
            for (int j = 0; j < 4; ++j) bv[j] = h2f(Bs[(tn * 4 + j) * 32 + kk]);
#pragma unroll
            for (int i = 0; i < 4; ++i)
#pragma unroll
                for (int j = 0; j < 4; ++j) acc[i][j] += av[i] * bv[j];
        }
    }

#pragma unroll
    for (int j = 0; j < 4; ++j) {
        int col = n0 + tn * 4 + j;
        if (col >= N) continue;
        float bvv = bias ? bias[col] : 0.f;
#pragma unroll
        for (int i = 0; i < 4; ++i) {
            int rowg = m0 + tm * 4 + i;
            float v = acc[i][j] * scale + bvv;
            if (relu) v = fmaxf(v, 0.f);
            long long off = coff + (long long)rowg * ldc + col;
            if (CF) {
                ((float*)Cv)[off] = v;
            } else if (resid) {
                float nv = resid[off] + v;
                resid[off] = nv;
                ((u16*)Cv)[off] = f2h_bits(nv);
            } else {
                ((u16*)Cv)[off] = f2h_bits(v);
            }
        }
    }
}

// ---------------------------------------------------------------------------
// Batched transpose into fp16. MODE 0: src already fp16. MODE 1: src raw input
// (fp32 or bf16 per detector). s_off: uniform extra element offset on src.
// ---------------------------------------------------------------------------
template <int MODE>
__global__ void transpose_k(const void* __restrict__ src_, int s_ld, long long s_off,
                            long long s_so, long long s_si,
                            u16* __restrict__ dst, int d_ld, long long d_so, long long d_si,
                            int R, int C, const void* caps)
{
    __shared__ u16 tile[32][33];
    const int z = blockIdx.z;
    const long long sb = s_off + (long long)(z >> 3) * s_so + (long long)(z & 7) * s_si;
    dst += (long long)(z >> 3) * d_so + (long long)(z & 7) * d_si;
    const int c0 = blockIdx.x * 32, r0 = blockIdx.y * 32;
    const int tx = threadIdx.x, ty = threadIdx.y;
    const int flag = (MODE == 1) ? detect_bf16(caps) : 0;
#pragma unroll
    for (int i = 0; i < 4; ++i) {
        int r = r0 + ty + i * 8, c = c0 + tx;
        if (r < R && c < C) {
            size_t idx = (size_t)(sb + (long long)r * s_ld + c);
            u16 v;
            if (MODE == 1) v = f2h_bits(ldin(src_, idx, flag));
            else           v = ((const u16*)src_)[idx];
            tile[ty + i * 8][tx] = v;
        }
    }
    __syncthreads();
#pragma unroll
    for (int i = 0; i < 4; ++i) {
        int r = r0 + tx, c = c0 + ty + i * 8;
        if (r < R && c < C) dst[(long long)c * d_ld + r] = tile[tx][ty + i * 8];
    }
}

__global__ void cvt_small_k(const void* srcW, const void* srcB, const void* candW, const void* candB,
                            const void* depW, const void* depB, const void* feasW, const void* feasB,
                            const void* pW, const void* pb, const void* boi, const void* b1i,
                            const void* b2i, const void* caps, float* __restrict__ dst)
{
    int i = blockIdx.x * 256 + threadIdx.x;
    if (i >= A_TOTAL) return;
    int flag = detect_bf16(caps);
    const void* s; int j;
    if      (i < A_SRCB)  { s = srcW;  j = i - A_SRCW; }
    else if (i < A_CANDW) { s = srcB;  j = i - A_SRCB; }
    else if (i < A_CANDB) { s = candW; j = i - A_CANDW; }
    else if (i < A_DEPW)  { s = candB; j = i - A_CANDB; }
    else if (i < A_DEPB)  { s = depW;  j = i - A_DEPW; }
    else if (i < A_FEASW) { s = depB;  j = i - A_DEPB; }
    else if (i < A_FEASB) { s = feasW; j = i - A_FEASW; }
    else if (i < A_PW)    { s = feasB; j = i - A_FEASB; }
    else if (i < A_PB)    { s = pW;    j = i - A_PW; }
    else if (i < A_BO)    { s = pb;    j = i - A_PB; }
    else if (i < A_B1)    { s = boi;   j = i - A_BO; }
    else if (i < A_B2)    { s = b1i;   j = i - A_B1; }
    else                  { s = b2i;   j = i - A_B2; }
    dst[i] = ldin(s, j, flag);
}

__global__ void catbias_k(const void* bq, const void* bk, const void* bv,
                          const void* caps, float* __restrict__ dst)
{
    int t = blockIdx.x * 256 + threadIdx.x;
    if (t >= 6 * 1536) return;
    int flag = detect_bf16(caps);
    int l = t / 1536, j = t - l * 1536;
    float v = (j < 512) ? ldin(bq, l * 512 + j, flag)
            : (j < 1024) ? ldin(bk, l * 512 + j - 512, flag)
                         : ldin(bv, l * 512 + j - 1024, flag);
    dst[t] = v;
}

__global__ __launch_bounds__(256) void encode_k(
    const void* __restrict__ sol, const void* __restrict__ caps, const void* __restrict__ emb,
    const float* __restrict__ arena, float* __restrict__ xf, u16* __restrict__ xb)
{
    const int row = blockIdx.x;
    const int b = row >> 9, s = row & 511;
    const int t = threadIdx.x;
    __shared__ float e[256];
    __shared__ float nds;
    const int flag = detect_bf16(caps);
    float idxf = ldin(sol, (size_t)row * 4, flag);
    int idx = (int)(idxf + 0.5f);
    if (idx < 0) idx = 0;
    if (idx > 9999) idx = 9999;
    e[t] = ldin(emb, (size_t)idx * 256 + t, flag);
    if (t == 0) {
        float rem = ldin(sol, ((size_t)b * 512) * 4 + 3, flag);
        float cap = ldin(caps, b, flag);
        float dem = ldin(sol, (size_t)row * 4 + 2, flag);
        nds = (s == 0) ? 0.f : 2.f * (dem - rem) / cap;
    }
    __syncthreads();
    const float *W, *Bb;
    if (s == 0)        { W = arena + A_SRCW;  Bb = arena + A_SRCB; }
    else if (s == 511) { W = arena + A_DEPW;  Bb = arena + A_DEPB; }
    else               { W = arena + A_CANDW; Bb = arena + A_CANDB; }
    float a0 = 0.f, a1 = 0.f;
    for (int c = 0; c < 256; ++c) {
        float ev = e[c];
        a0 += ev * W[(size_t)c * 512 + t];
        a1 += ev * W[(size_t)c * 512 + t + 256];
    }
    float nd = nds;
    a0 += nd * W[256 * 512 + t] + Bb[t];
    a1 += nd * W[256 * 512 + t + 256] + Bb[t + 256];
    size_t o = (size_t)row * 512;
    xf[o + t] = a0;        xb[o + t] = f2h_bits(a0);
    xf[o + t + 256] = a1;  xb[o + t + 256] = f2h_bits(a1);
}

// Row softmax over 512 FP32 scores; writes fp16 WEIGHTS in place (first 512
// u16 of each 512-float row => PV reads with lda=1024 u16).
// (s_scale*log(n) shift is constant along the softmax axis -> dropped.)
__global__ __launch_bounds__(256) void softmax_k(float* __restrict__ scf)
{
    const int wrow = blockIdx.x * 4 + (threadIdx.x >> 6);
    const int lane = threadIdx.x & 63;
    float* rf = scf + (size_t)wrow * 512;
    float v[8];
    float mx = -3.0e38f;
#pragma unroll
    for (int i = 0; i < 8; ++i) { v[i] = rf[lane + 64 * i]; mx = fmaxf(mx, v[i]); }
#pragma unroll
    for (int o = 1; o < 64; o <<= 1) mx = fmaxf(mx, __shfl_xor(mx, o, 64));
    float s = 0.f;
#pragma unroll
    for (int i = 0; i < 8; ++i) { v[i] = expf(v[i] - mx); s += v[i]; }
#pragma unroll
    for (int o = 1; o < 64; o <<= 1) s += __shfl_xor(s, o, 64);
    float inv = 1.f / s;
    u16* wp = (u16*)rf;
#pragma unroll
    for (int i = 0; i < 8; ++i) wp[lane + 64 * i] = f2h_bits(v[i] * inv);
}

// feas head -> FP32 output (d_out is float*: reference output dtype)
__global__ __launch_bounds__(256) void feas_k(const float* __restrict__ xf,
                                              const float* __restrict__ arena,
                                              float* __restrict__ out)
{
    int w = blockIdx.x * 4 + (threadIdx.x >> 6);
    if (w >= 8 * 510) return;
    int lane = threadIdx.x & 63;
    int b = w / 510, j = w - b * 510;
    const float* xr = xf + ((size_t)(b * 512 + 1 + j)) * 512;
    const float* fW = arena + A_FEASW;
    float a = 0.f;
#pragma unroll
    for (int i = 0; i < 8; ++i) { int d = lane + 64 * i; a += xr[d] * fW[d]; }
#pragma unroll
    for (int o = 1; o < 64; o <<= 1) a += __shfl_xor(a, o, 64);
    if (lane == 0) out[8160 + b * 510 + j] = a + arena[A_FEASB];
}

// logits head -> FP32 output
__global__ __launch_bounds__(256) void ptr_k(const float* __restrict__ xf,
                                             const float* __restrict__ arena,
                                             float* __restrict__ out)
{
    int w = blockIdx.x * 4 + (threadIdx.x >> 6);
    if (w >= 8 * 510) return;
    int lane = threadIdx.x & 63;
    int b = w / 510, j = w - b * 510;
    const float* xr = xf + ((size_t)(b * 512 + 1 + j)) * 512;
    const float* pWa = arena + A_PW;
    float a0 = 0.f, a1 = 0.f;
#pragma unroll
    for (int i = 0; i < 8; ++i) {
        int d = lane + 64 * i;
        float x = xr[d];
        a0 += x * pWa[d * 2];
        a1 += x * pWa[d * 2 + 1];
    }
#pragma unroll
    for (int o = 1; o < 64; o <<= 1) { a0 += __shfl_xor(a0, o, 64); a1 += __shfl_xor(a1, o, 64); }
    if (lane == 0) {
        out[(size_t)b * 1020 + j]       = a0 + arena[A_PB];
        out[(size_t)b * 1020 + 510 + j] = a1 + arena[A_PB + 1];
    }
}

extern "C" void kernel_launch(void* const* d_in, const int* in_sizes, int n_in,
                              void* d_out, int out_size, void* d_ws, size_t ws_size,
                              hipStream_t stream)
{
    const void* sol   = d_in[0];
    const void* caps  = d_in[1];
    const void* emb   = d_in[2];
    const void* srcW  = d_in[3];
    const void* srcB  = d_in[4];
    const void* candW = d_in[5];
    const void* candB = d_in[6];
    const void* depW  = d_in[7];
    const void* depB  = d_in[8];
    const void* feasW = d_in[9];
    const void* feasB = d_in[10];
    const void* Wq  = d_in[11];
    const void* bq  = d_in[12];
    const void* Wk  = d_in[13];
    const void* bk  = d_in[14];
    const void* Wv  = d_in[15];
    const void* bv  = d_in[16];
    const void* Wo  = d_in[17];
    const void* boi = d_in[18];
    // d_in[19] = s_scale: softmax shift no-op
    const void* W1  = d_in[20];
    const void* b1i = d_in[21];
    const void* W2  = d_in[22];
    const void* b2i = d_in[23];
    const void* pW  = d_in[24];
    const void* pb  = d_in[25];
    float* out = (float*)d_out;  // reference output dtype is float32

    // workspace (~55.7 MiB; layout identical to rounds 3-5 which ran cleanly)
    char* w = (char*)d_ws;
    float* xf    = (float*)w; w += 8388608;   // 4096x512 fp32 residual master
    u16* xb      = (u16*)w;   w += 4194304;   // 4096x512 fp16
    u16* qkvb    = (u16*)w;   w += 12582912;  // 4096x1536 fp16 (q|k|v)
    u16* vt      = (u16*)w;   w += 4194304;   // 64x64x512 fp16 (v^T per head)
    float* scf   = (float*)w; w += 16777216;  // 16x512x512 fp32 scores (quarter)
    u16* hb      = (u16*)scf;                 //  ALIAS: 4096x2048 fp16 FFN hidden
    u16* ob      = (u16*)w;   w += 4194304;   // 4096x512 fp16 attention out
    u16* wqkvT   = (u16*)w;   w += 1572864;   // 1536x512 fp16 (per-layer)
    u16* woT     = (u16*)w;   w += 524288;    // 512x512 fp16  (per-layer)
    u16* w1T     = (u16*)w;   w += 2097152;   // 2048x512 fp16 (per-layer)
    u16* w2T     = (u16*)w;   w += 2097152;   // 512x2048 fp16 (per-layer)
    float* bqkvf = (float*)w; w += 36864;     // 6x1536 fp32
    float* arena = (float*)w; w += A_TOTAL * 4;

    dim3 tb(32, 8);
    cvt_small_k<<<dim3((A_TOTAL + 255) / 256), 256, 0, stream>>>(
        srcW, srcB, candW, candB, depW, depB, feasW, feasB, pW, pb, boi, b1i, b2i, caps, arena);
    catbias_k<<<dim3(36), 256, 0, stream>>>(bq, bk, bv, caps, bqkvf);
    encode_k<<<dim3(4096), 256, 0, stream>>>(sol, caps, emb, arena, xf, xb);

    for (int i = 0; i < 6; ++i) {
        const long long oW = (long long)i * 262144, oF = (long long)i * 1048576;
        transpose_k<1><<<dim3(16, 16, 1), tb, 0, stream>>>(Wq, 512, oW, 0, 0, wqkvT,          512, 0, 0, 512, 512, caps);
        transpose_k<1><<<dim3(16, 16, 1), tb, 0, stream>>>(Wk, 512, oW, 0, 0, wqkvT + 262144, 512, 0, 0, 512, 512, caps);
        transpose_k<1><<<dim3(16, 16, 1), tb, 0, stream>>>(Wv, 512, oW, 0, 0, wqkvT + 524288, 512, 0, 0, 512, 512, caps);
        transpose_k<1><<<dim3(16, 16, 1), tb, 0, stream>>>(Wo, 512, oW, 0, 0, woT, 512, 0, 0, 512, 512, caps);
        transpose_k<1><<<dim3(64, 16, 1), tb, 0, stream>>>(W1, 2048, oF, 0, 0, w1T, 512, 0, 0, 512, 2048, caps);
        transpose_k<1><<<dim3(16, 64, 1), tb, 0, stream>>>(W2, 512, oF, 0, 0, w2T, 2048, 0, 0, 2048, 512, caps);

        // QKV fused: [4096,512] @ [512,1536]
        gemm_v<0><<<dim3(24, 64, 1), 256, 0, stream>>>(
            xb, 512, 0, 0, wqkvT, 512, 0, 0,
            qkvb, 1536, 0, 0, bqkvf + i * 1536, nullptr, 1.f, 0, 1536, 512);
        // v^T per (b,h)
        transpose_k<0><<<dim3(2, 16, 64), tb, 0, stream>>>(
            qkvb + 1024, 1536, 0, 786432, 64, vt, 512, 262144, 32768, 512, 64, caps);

        for (int q4 = 0; q4 < 4; ++q4) {  // attention in batch-quarters (2 b x 8 h)
            const long long b2_ = 2LL * q4;
            // scores fp32 = (q @ k^T)/8
            gemm_v<1><<<dim3(8, 8, 16), 256, 0, stream>>>(
                qkvb + b2_ * 786432, 1536, 786432, 64, qkvb + b2_ * 786432 + 512, 1536, 786432, 64,
                scf, 512, 2097152, 262144, nullptr, nullptr, 0.125f, 0, 512, 64);
            softmax_k<<<dim3(2048), 256, 0, stream>>>(scf);
            // PV: weights (fp16, packed in-place, lda=1024) @ v^T
            gemm_v<0><<<dim3(1, 8, 16), 256, 0, stream>>>(
                (u16*)scf, 1024, 4194304, 524288, vt + b2_ * 262144, 512, 262144, 32768,
                ob + b2_ * 262144, 512, 262144, 64, nullptr, nullptr, 1.f, 0, 64, 512);
        }
        // O-proj + residual
        gemm_v<0><<<dim3(8, 64, 1), 256, 0, stream>>>(
            ob, 512, 0, 0, woT, 512, 0, 0,
            xb, 512, 0, 0, arena + A_BO + i * 512, xf, 1.f, 0, 512, 512);
        if (i == 0)
            feas_k<<<dim3(1020), 256, 0, stream>>>(xf, arena, out);
        // FFN1 (relu); hb aliases scf (scores dead after PV)
        gemm_v<0><<<dim3(32, 64, 1), 256, 0, stream>>>(
            xb, 512, 0, 0, w1T, 512, 0, 0,
            hb, 2048, 0, 0, arena + A_B1 + i * 2048, nullptr, 1.f, 1, 2048, 512);
        // FFN2 + residual
        gemm_v<0><<<dim3(8, 64, 1), 256, 0, stream>>>(
            hb, 2048, 0, 0, w2T, 2048, 0, 0,
            xb, 512, 0, 0, arena + A_B2 + i * 512, xf, 1.f, 0, 512, 2048);
    }
    ptr_k<<<dim3(1020), 256, 0, stream>>>(xf, arena, out);
}

// Round 7
// 2069.691 us; speedup vs baseline: 5.7457x; 5.7457x over previous
//
#include <hip/hip_runtime.h>

typedef unsigned short u16;
typedef _Float16 half8 __attribute__((ext_vector_type(8)));
typedef float f32x4 __attribute__((ext_vector_type(4)));

__device__ inline float bf2f(u16 b) { return __builtin_bit_cast(float, ((unsigned)b) << 16); }
__device__ inline float h2f(u16 h) { return (float)__builtin_bit_cast(_Float16, h); }
__device__ inline u16 f2h_bits(float f) { return __builtin_bit_cast(u16, (_Float16)f); }

// Input dtype detector: capacities ~ [50,100]. bf16 inputs -> u16[0,2,4,6] are
// in-range bf16 values; fp32 inputs -> those are random low mantissa halves.
__device__ inline int detect_bf16(const void* caps) {
    const u16* c = (const u16*)caps;
    int cnt = 0;
#pragma unroll
    for (int k = 0; k < 4; ++k) {
        float v = bf2f(c[2 * k]);
        if (v >= 20.f && v <= 200.f) cnt++;
    }
    return cnt >= 2;
}
__device__ inline float ldin(const void* p, size_t i, int flag) {
    return flag ? bf2f(((const u16*)p)[i]) : ((const float*)p)[i];
}

#define GLOAD_LDS16(g, l)                                                              \
    __builtin_amdgcn_global_load_lds((__attribute__((address_space(1))) const void*)(g), \
                                     (__attribute__((address_space(3))) void*)(l), 16, 0, 0)

// canonical fp32 arena offsets (elements)
#define A_SRCW 0
#define A_SRCB 131584
#define A_CANDW 132096
#define A_CANDB 263680
#define A_DEPW 264192
#define A_DEPB 395776
#define A_FEASW 396288
#define A_FEASB 396800
#define A_PW 396801
#define A_PB 397825
#define A_BO 397827
#define A_B1 400899
#define A_B2 413187
#define A_TOTAL 416259

// ---------------------------------------------------------------------------
// fp16 MFMA GEMM (m97-style): acc = scale*(A @ Bt^T) + bias.
// CF=0: C fp16 (u16*), optional fp32 resid accumulate. CF=1: C fp32.
// A: M x K row-major fp16. Bt: N x K row-major fp16. bias fp32.
// Batch offset per blockIdx.z: off = (z>>3)*so + (z&7)*si.
// BM=BN=128, BK=32, 256 threads (4 waves, 2x2 of 64x64). M % 128 == 0.
// Numerics proven identical to the VALU reference engine (rounds 4/5).
// ---------------------------------------------------------------------------
template <int CF>
__global__ __launch_bounds__(256) void gemm_f16(
    const u16* __restrict__ A, int lda, long long a_so, long long a_si,
    const u16* __restrict__ B, int ldb, long long b_so, long long b_si,
    void* __restrict__ Cv, int ldc, long long c_so, long long c_si,
    const float* __restrict__ bias, float* __restrict__ resid,
    float scale, int relu, int N, int K)
{
    __shared__ __attribute__((aligned(16))) u16 As[128 * 32];
    __shared__ __attribute__((aligned(16))) u16 Bs[128 * 32];

    const int z = blockIdx.z;
    A += (long long)(z >> 3) * a_so + (long long)(z & 7) * a_si;
    B += (long long)(z >> 3) * b_so + (long long)(z & 7) * b_si;
    const long long coff = (long long)(z >> 3) * c_so + (long long)(z & 7) * c_si;

    const int m0 = blockIdx.y * 128;
    const int n0 = blockIdx.x * 128;
    const int t = threadIdx.x, lane = t & 63, wid = t >> 6;
    const int qd = lane >> 4, ml = lane & 15;
    const int wm = (wid >> 1) * 64, wn = (wid & 1) * 64;

    f32x4 acc[4][4] = {};

    for (int k0 = 0; k0 < K; k0 += 32) {
        __syncthreads();  // prev tile's ds_reads done before overwrite
#pragma unroll
        for (int rep = 0; rep < 2; ++rep) {
            int seg = (wid + rep * 4) * 64 + lane;   // 16B segments
            int row = seg >> 2, c8 = (seg & 3) * 8;
            const u16* ga = A + (long long)(m0 + row) * lda + k0 + c8;
            GLOAD_LDS16(ga, As + (size_t)(seg & ~63) * 8);  // wave-uniform base
            int rn = n0 + row;
            if (rn > N - 1) rn = N - 1;  // clamp OOB (values unused)
            const u16* gb = B + (long long)rn * ldb + k0 + c8;
            GLOAD_LDS16(gb, Bs + (size_t)(seg & ~63) * 8);
        }
        __syncthreads();  // drains vmcnt(0): staging visible

        half8 af[4], bfv[4];
#pragma unroll
        for (int mt = 0; mt < 4; ++mt)
            af[mt] = *(const half8*)(As + (wm + mt * 16 + ml) * 32 + qd * 8);
#pragma unroll
        for (int nt = 0; nt < 4; ++nt)
            bfv[nt] = *(const half8*)(Bs + (wn + nt * 16 + ml) * 32 + qd * 8);
#pragma unroll
        for (int mt = 0; mt < 4; ++mt)
#pragma unroll
            for (int nt = 0; nt < 4; ++nt)
                acc[mt][nt] = __builtin_amdgcn_mfma_f32_16x16x32_f16(af[mt], bfv[nt], acc[mt][nt], 0, 0, 0);
    }

    // Epilogue. C/D layout: col = lane&15, row = quad*4 + reg.
#pragma unroll
    for (int nt = 0; nt < 4; ++nt) {
        int col = n0 + wn + nt * 16 + ml;
        if (col >= N) continue;
        float bv = bias ? bias[col] : 0.f;
#pragma unroll
        for (int mt = 0; mt < 4; ++mt) {
#pragma unroll
            for (int r = 0; r < 4; ++r) {
                int rowg = m0 + wm + mt * 16 + qd * 4 + r;
                float v = acc[mt][nt][r] * scale + bv;
                if (relu) v = fmaxf(v, 0.f);
                long long off = coff + (long long)rowg * ldc + col;
                if (CF) {
                    ((float*)Cv)[off] = v;
                } else if (resid) {
                    float nv = resid[off] + v;
                    resid[off] = nv;
                    ((u16*)Cv)[off] = f2h_bits(nv);
                } else {
                    ((u16*)Cv)[off] = f2h_bits(v);
                }
            }
        }
    }
}

// ---------------------------------------------------------------------------
// Batched transpose into fp16. MODE 0: src already fp16. MODE 1: src raw input
// (fp32 or bf16 per detector). s_off: uniform extra element offset on src.
// ---------------------------------------------------------------------------
template <int MODE>
__global__ void transpose_k(const void* __restrict__ src_, int s_ld, long long s_off,
                            long long s_so, long long s_si,
                            u16* __restrict__ dst, int d_ld, long long d_so, long long d_si,
                            int R, int C, const void* caps)
{
    __shared__ u16 tile[32][33];
    const int z = blockIdx.z;
    const long long sb = s_off + (long long)(z >> 3) * s_so + (long long)(z & 7) * s_si;
    dst += (long long)(z >> 3) * d_so + (long long)(z & 7) * d_si;
    const int c0 = blockIdx.x * 32, r0 = blockIdx.y * 32;
    const int tx = threadIdx.x, ty = threadIdx.y;
    const int flag = (MODE == 1) ? detect_bf16(caps) : 0;
#pragma unroll
    for (int i = 0; i < 4; ++i) {
        int r = r0 + ty + i * 8, c = c0 + tx;
        if (r < R && c < C) {
            size_t idx = (size_t)(sb + (long long)r * s_ld + c);
            u16 v;
            if (MODE == 1) v = f2h_bits(ldin(src_, idx, flag));
            else           v = ((const u16*)src_)[idx];
            tile[ty + i * 8][tx] = v;
        }
    }
    __syncthreads();
#pragma unroll
    for (int i = 0; i < 4; ++i) {
        int r = r0 + tx, c = c0 + ty + i * 8;
        if (r < R && c < C) dst[(long long)c * d_ld + r] = tile[tx][ty + i * 8];
    }
}

__global__ void cvt_small_k(const void* srcW, const void* srcB, const void* candW, const void* candB,
                            const void* depW, const void* depB, const void* feasW, const void* feasB,
                            const void* pW, const void* pb, const void* boi, const void* b1i,
                            const void* b2i, const void* caps, float* __restrict__ dst)
{
    int i = blockIdx.x * 256 + threadIdx.x;
    if (i >= A_TOTAL) return;
    int flag = detect_bf16(caps);
    const void* s; int j;
    if      (i < A_SRCB)  { s = srcW;  j = i - A_SRCW; }
    else if (i < A_CANDW) { s = srcB;  j = i - A_SRCB; }
    else if (i < A_CANDB) { s = candW; j = i - A_CANDW; }
    else if (i < A_DEPW)  { s = candB; j = i - A_CANDB; }
    else if (i < A_DEPB)  { s = depW;  j = i - A_DEPW; }
    else if (i < A_FEASW) { s = depB;  j = i - A_DEPB; }
    else if (i < A_FEASB) { s = feasW; j = i - A_FEASW; }
    else if (i < A_PW)    { s = feasB; j = i - A_FEASB; }
    else if (i < A_PB)    { s = pW;    j = i - A_PW; }
    else if (i < A_BO)    { s = pb;    j = i - A_PB; }
    else if (i < A_B1)    { s = boi;   j = i - A_BO; }
    else if (i < A_B2)    { s = b1i;   j = i - A_B1; }
    else                  { s = b2i;   j = i - A_B2; }
    dst[i] = ldin(s, j, flag);
}

__global__ void catbias_k(const void* bq, const void* bk, const void* bv,
                          const void* caps, float* __restrict__ dst)
{
    int t = blockIdx.x * 256 + threadIdx.x;
    if (t >= 6 * 1536) return;
    int flag = detect_bf16(caps);
    int l = t / 1536, j = t - l * 1536;
    float v = (j < 512) ? ldin(bq, l * 512 + j, flag)
            : (j < 1024) ? ldin(bk, l * 512 + j - 512, flag)
                         : ldin(bv, l * 512 + j - 1024, flag);
    dst[t] = v;
}

__global__ __launch_bounds__(256) void encode_k(
    const void* __restrict__ sol, const void* __restrict__ caps, const void* __restrict__ emb,
    const float* __restrict__ arena, float* __restrict__ xf, u16* __restrict__ xb)
{
    const int row = blockIdx.x;
    const int b = row >> 9, s = row & 511;
    const int t = threadIdx.x;
    __shared__ float e[256];
    __shared__ float nds;
    const int flag = detect_bf16(caps);
    float idxf = ldin(sol, (size_t)row * 4, flag);
    int idx = (int)(idxf + 0.5f);
    if (idx < 0) idx = 0;
    if (idx > 9999) idx = 9999;
    e[t] = ldin(emb, (size_t)idx * 256 + t, flag);
    if (t == 0) {
        float rem = ldin(sol, ((size_t)b * 512) * 4 + 3, flag);
        float cap = ldin(caps, b, flag);
        float dem = ldin(sol, (size_t)row * 4 + 2, flag);
        nds = (s == 0) ? 0.f : 2.f * (dem - rem) / cap;
    }
    __syncthreads();
    const float *W, *Bb;
    if (s == 0)        { W = arena + A_SRCW;  Bb = arena + A_SRCB; }
    else if (s == 511) { W = arena + A_DEPW;  Bb = arena + A_DEPB; }
    else               { W = arena + A_CANDW; Bb = arena + A_CANDB; }
    float a0 = 0.f, a1 = 0.f;
    for (int c = 0; c < 256; ++c) {
        float ev = e[c];
        a0 += ev * W[(size_t)c * 512 + t];
        a1 += ev * W[(size_t)c * 512 + t + 256];
    }
    float nd = nds;
    a0 += nd * W[256 * 512 + t] + Bb[t];
    a1 += nd * W[256 * 512 + t + 256] + Bb[t + 256];
    size_t o = (size_t)row * 512;
    xf[o + t] = a0;        xb[o + t] = f2h_bits(a0);
    xf[o + t + 256] = a1;  xb[o + t + 256] = f2h_bits(a1);
}

// Row softmax over 512 FP32 scores; writes fp16 WEIGHTS in place (first 512
// u16 of each 512-float row => PV reads with lda=1024 u16).
// (s_scale*log(n) shift is constant along the softmax axis -> dropped.)
__global__ __launch_bounds__(256) void softmax_k(float* __restrict__ scf)
{
    const int wrow = blockIdx.x * 4 + (threadIdx.x >> 6);
    const int lane = threadIdx.x & 63;
    float* rf = scf + (size_t)wrow * 512;
    float v[8];
    float mx = -3.0e38f;
#pragma unroll
    for (int i = 0; i < 8; ++i) { v[i] = rf[lane + 64 * i]; mx = fmaxf(mx, v[i]); }
#pragma unroll
    for (int o = 1; o < 64; o <<= 1) mx = fmaxf(mx, __shfl_xor(mx, o, 64));
    float s = 0.f;
#pragma unroll
    for (int i = 0; i < 8; ++i) { v[i] = expf(v[i] - mx); s += v[i]; }
#pragma unroll
    for (int o = 1; o < 64; o <<= 1) s += __shfl_xor(s, o, 64);
    float inv = 1.f / s;
    u16* wp = (u16*)rf;
#pragma unroll
    for (int i = 0; i < 8; ++i) wp[lane + 64 * i] = f2h_bits(v[i] * inv);
}

// feas head -> FP32 output (d_out is float*)
__global__ __launch_bounds__(256) void feas_k(const float* __restrict__ xf,
                                              const float* __restrict__ arena,
                                              float* __restrict__ out)
{
    int w = blockIdx.x * 4 + (threadIdx.x >> 6);
    if (w >= 8 * 510) return;
    int lane = threadIdx.x & 63;
    int b = w / 510, j = w - b * 510;
    const float* xr = xf + ((size_t)(b * 512 + 1 + j)) * 512;
    const float* fW = arena + A_FEASW;
    float a = 0.f;
#pragma unroll
    for (int i = 0; i < 8; ++i) { int d = lane + 64 * i; a += xr[d] * fW[d]; }
#pragma unroll
    for (int o = 1; o < 64; o <<= 1) a += __shfl_xor(a, o, 64);
    if (lane == 0) out[8160 + b * 510 + j] = a + arena[A_FEASB];
}

// logits head -> FP32 output
__global__ __launch_bounds__(256) void ptr_k(const float* __restrict__ xf,
                                             const float* __restrict__ arena,
                                             float* __restrict__ out)
{
    int w = blockIdx.x * 4 + (threadIdx.x >> 6);
    if (w >= 8 * 510) return;
    int lane = threadIdx.x & 63;
    int b = w / 510, j = w - b * 510;
    const float* xr = xf + ((size_t)(b * 512 + 1 + j)) * 512;
    const float* pWa = arena + A_PW;
    float a0 = 0.f, a1 = 0.f;
#pragma unroll
    for (int i = 0; i < 8; ++i) {
        int d = lane + 64 * i;
        float x = xr[d];
        a0 += x * pWa[d * 2];
        a1 += x * pWa[d * 2 + 1];
    }
#pragma unroll
    for (int o = 1; o < 64; o <<= 1) { a0 += __shfl_xor(a0, o, 64); a1 += __shfl_xor(a1, o, 64); }
    if (lane == 0) {
        out[(size_t)b * 1020 + j]       = a0 + arena[A_PB];
        out[(size_t)b * 1020 + 510 + j] = a1 + arena[A_PB + 1];
    }
}

extern "C" void kernel_launch(void* const* d_in, const int* in_sizes, int n_in,
                              void* d_out, int out_size, void* d_ws, size_t ws_size,
                              hipStream_t stream)
{
    const void* sol   = d_in[0];
    const void* caps  = d_in[1];
    const void* emb   = d_in[2];
    const void* srcW  = d_in[3];
    const void* srcB  = d_in[4];
    const void* candW = d_in[5];
    const void* candB = d_in[6];
    const void* depW  = d_in[7];
    const void* depB  = d_in[8];
    const void* feasW = d_in[9];
    const void* feasB = d_in[10];
    const void* Wq  = d_in[11];
    const void* bq  = d_in[12];
    const void* Wk  = d_in[13];
    const void* bk  = d_in[14];
    const void* Wv  = d_in[15];
    const void* bv  = d_in[16];
    const void* Wo  = d_in[17];
    const void* boi = d_in[18];
    // d_in[19] = s_scale: softmax shift no-op
    const void* W1  = d_in[20];
    const void* b1i = d_in[21];
    const void* W2  = d_in[22];
    const void* b2i = d_in[23];
    const void* pW  = d_in[24];
    const void* pb  = d_in[25];
    float* out = (float*)d_out;  // reference output dtype is float32

    // workspace (~55.7 MiB; layout identical to round 6 which passed)
    char* w = (char*)d_ws;
    float* xf    = (float*)w; w += 8388608;   // 4096x512 fp32 residual master
    u16* xb      = (u16*)w;   w += 4194304;   // 4096x512 fp16
    u16* qkvb    = (u16*)w;   w += 12582912;  // 4096x1536 fp16 (q|k|v)
    u16* vt      = (u16*)w;   w += 4194304;   // 64x64x512 fp16 (v^T per head)
    float* scf   = (float*)w; w += 16777216;  // 16x512x512 fp32 scores (quarter)
    u16* hb      = (u16*)scf;                 //  ALIAS: 4096x2048 fp16 FFN hidden
    u16* ob      = (u16*)w;   w += 4194304;   // 4096x512 fp16 attention out
    u16* wqkvT   = (u16*)w;   w += 1572864;   // 1536x512 fp16 (per-layer)
    u16* woT     = (u16*)w;   w += 524288;    // 512x512 fp16  (per-layer)
    u16* w1T     = (u16*)w;   w += 2097152;   // 2048x512 fp16 (per-layer)
    u16* w2T     = (u16*)w;   w += 2097152;   // 512x2048 fp16 (per-layer)
    float* bqkvf = (float*)w; w += 36864;     // 6x1536 fp32
    float* arena = (float*)w; w += A_TOTAL * 4;

    dim3 tb(32, 8);
    cvt_small_k<<<dim3((A_TOTAL + 255) / 256), 256, 0, stream>>>(
        srcW, srcB, candW, candB, depW, depB, feasW, feasB, pW, pb, boi, b1i, b2i, caps, arena);
    catbias_k<<<dim3(36), 256, 0, stream>>>(bq, bk, bv, caps, bqkvf);
    encode_k<<<dim3(4096), 256, 0, stream>>>(sol, caps, emb, arena, xf, xb);

    for (int i = 0; i < 6; ++i) {
        const long long oW = (long long)i * 262144, oF = (long long)i * 1048576;
        transpose_k<1><<<dim3(16, 16, 1), tb, 0, stream>>>(Wq, 512, oW, 0, 0, wqkvT,          512, 0, 0, 512, 512, caps);
        transpose_k<1><<<dim3(16, 16, 1), tb, 0, stream>>>(Wk, 512, oW, 0, 0, wqkvT + 262144, 512, 0, 0, 512, 512, caps);
        transpose_k<1><<<dim3(16, 16, 1), tb, 0, stream>>>(Wv, 512, oW, 0, 0, wqkvT + 524288, 512, 0, 0, 512, 512, caps);
        transpose_k<1><<<dim3(16, 16, 1), tb, 0, stream>>>(Wo, 512, oW, 0, 0, woT, 512, 0, 0, 512, 512, caps);
        transpose_k<1><<<dim3(64, 16, 1), tb, 0, stream>>>(W1, 2048, oF, 0, 0, w1T, 512, 0, 0, 512, 2048, caps);
        transpose_k<1><<<dim3(16, 64, 1), tb, 0, stream>>>(W2, 512, oF, 0, 0, w2T, 2048, 0, 0, 2048, 512, caps);

        // QKV fused: [4096,512] @ [512,1536]
        gemm_f16<0><<<dim3(12, 32, 1), 256, 0, stream>>>(
            xb, 512, 0, 0, wqkvT, 512, 0, 0,
            qkvb, 1536, 0, 0, bqkvf + i * 1536, nullptr, 1.f, 0, 1536, 512);
        // v^T per (b,h)
        transpose_k<0><<<dim3(2, 16, 64), tb, 0, stream>>>(
            qkvb + 1024, 1536, 0, 786432, 64, vt, 512, 262144, 32768, 512, 64, caps);

        for (int q4 = 0; q4 < 4; ++q4) {  // attention in batch-quarters (2 b x 8 h)
            const long long b2_ = 2LL * q4;
            // scores fp32 = (q @ k^T)/8
            gemm_f16<1><<<dim3(4, 4, 16), 256, 0, stream>>>(
                qkvb + b2_ * 786432, 1536, 786432, 64, qkvb + b2_ * 786432 + 512, 1536, 786432, 64,
                scf, 512, 2097152, 262144, nullptr, nullptr, 0.125f, 0, 512, 64);
            softmax_k<<<dim3(2048), 256, 0, stream>>>(scf);
            // PV: weights (fp16, packed in-place, lda=1024) @ v^T
            gemm_f16<0><<<dim3(1, 4, 16), 256, 0, stream>>>(
                (u16*)scf, 1024, 4194304, 524288, vt + b2_ * 262144, 512, 262144, 32768,
                ob + b2_ * 262144, 512, 262144, 64, nullptr, nullptr, 1.f, 0, 64, 512);
        }
        // O-proj + residual
        gemm_f16<0><<<dim3(4, 32, 1), 256, 0, stream>>>(
            ob, 512, 0, 0, woT, 512, 0, 0,
            xb, 512, 0, 0, arena + A_BO + i * 512, xf, 1.f, 0, 512, 512);
        if (i == 0)
            feas_k<<<dim3(1020), 256, 0, stream>>>(xf, arena, out);
        // FFN1 (relu); hb aliases scf (scores dead after PV)
        gemm_f16<0><<<dim3(16, 32, 1), 256, 0, stream>>>(
            xb, 512, 0, 0, w1T, 512, 0, 0,
            hb, 2048, 0, 0, arena + A_B1 + i * 2048, nullptr, 1.f, 1, 2048, 512);
        // FFN2 + residual
        gemm_f16<0><<<dim3(4, 32, 1), 256, 0, stream>>>(
            hb, 2048, 0, 0, w2T, 2048, 0, 0,
            xb, 512, 0, 0, arena + A_B2 + i * 512, xf, 1.f, 0, 512, 2048);
    }
    ptr_k<<<dim3(1020), 256, 0, stream>>>(xf, arena, out);
}

// Round 8
// 1801.474 us; speedup vs baseline: 6.6012x; 1.1489x over previous
//
#include <hip/hip_runtime.h>

typedef unsigned short u16;
typedef _Float16 half8 __attribute__((ext_vector_type(8)));
typedef float f32x4 __attribute__((ext_vector_type(4)));

__device__ inline float bf2f(u16 b) { return __builtin_bit_cast(float, ((unsigned)b) << 16); }
__device__ inline float h2f(u16 h) { return (float)__builtin_bit_cast(_Float16, h); }
__device__ inline u16 f2h_bits(float f) { return __builtin_bit_cast(u16, (_Float16)f); }

// Input dtype detector: capacities ~ [50,100]. bf16 inputs -> u16[0,2,4,6] are
// in-range bf16 values; fp32 inputs -> those are random low mantissa halves.
__device__ inline int detect_bf16(const void* caps) {
    const u16* c = (const u16*)caps;
    int cnt = 0;
#pragma unroll
    for (int k = 0; k < 4; ++k) {
        float v = bf2f(c[2 * k]);
        if (v >= 20.f && v <= 200.f) cnt++;
    }
    return cnt >= 2;
}
__device__ inline float ldin(const void* p, size_t i, int flag) {
    return flag ? bf2f(((const u16*)p)[i]) : ((const float*)p)[i];
}

#define GLOAD_LDS16(g, l)                                                              \
    __builtin_amdgcn_global_load_lds((__attribute__((address_space(1))) const void*)(g), \
                                     (__attribute__((address_space(3))) void*)(l), 16, 0, 0)

// canonical fp32 arena offsets (elements)
#define A_SRCW 0
#define A_SRCB 131584
#define A_CANDW 132096
#define A_CANDB 263680
#define A_DEPW 264192
#define A_DEPB 395776
#define A_FEASW 396288
#define A_FEASB 396800
#define A_PW 396801
#define A_PB 397825
#define A_BO 397827
#define A_B1 400899
#define A_B2 413187
#define A_TOTAL 416259

// ---------------------------------------------------------------------------
// fp16 MFMA GEMM (m97-style): acc = scale*(A @ Bt^T) + bias.
// CF=0: C fp16 (+optional fp32 resid accumulate). CF=1: C fp32.
// CF=2: dual store — resid[off] = v (fp32) AND C fp16 = v (no read).
// A: M x K row-major fp16. Bt: N x K row-major fp16. bias fp32.
// Batch offset per blockIdx.z: off = (z>>3)*so + (z&7)*si.
// BM=BN=128, BK=32, 256 threads (4 waves, 2x2 of 64x64). M % 128 == 0.
// ---------------------------------------------------------------------------
template <int CF>
__global__ __launch_bounds__(256) void gemm_f16(
    const u16* __restrict__ A, int lda, long long a_so, long long a_si,
    const u16* __restrict__ B, int ldb, long long b_so, long long b_si,
    void* __restrict__ Cv, int ldc, long long c_so, long long c_si,
    const float* __restrict__ bias, float* __restrict__ resid,
    float scale, int relu, int N, int K)
{
    __shared__ __attribute__((aligned(16))) u16 As[128 * 32];
    __shared__ __attribute__((aligned(16))) u16 Bs[128 * 32];

    const int z = blockIdx.z;
    A += (long long)(z >> 3) * a_so + (long long)(z & 7) * a_si;
    B += (long long)(z >> 3) * b_so + (long long)(z & 7) * b_si;
    const long long coff = (long long)(z >> 3) * c_so + (long long)(z & 7) * c_si;

    const int m0 = blockIdx.y * 128;
    const int n0 = blockIdx.x * 128;
    const int t = threadIdx.x, lane = t & 63, wid = t >> 6;
    const int qd = lane >> 4, ml = lane & 15;
    const int wm = (wid >> 1) * 64, wn = (wid & 1) * 64;

    f32x4 acc[4][4] = {};

    for (int k0 = 0; k0 < K; k0 += 32) {
        __syncthreads();
#pragma unroll
        for (int rep = 0; rep < 2; ++rep) {
            int seg = (wid + rep * 4) * 64 + lane;
            int row = seg >> 2, c8 = (seg & 3) * 8;
            const u16* ga = A + (long long)(m0 + row) * lda + k0 + c8;
            GLOAD_LDS16(ga, As + (size_t)(seg & ~63) * 8);
            int rn = n0 + row;
            if (rn > N - 1) rn = N - 1;
            const u16* gb = B + (long long)rn * ldb + k0 + c8;
            GLOAD_LDS16(gb, Bs + (size_t)(seg & ~63) * 8);
        }
        __syncthreads();

        half8 af[4], bfv[4];
#pragma unroll
        for (int mt = 0; mt < 4; ++mt)
            af[mt] = *(const half8*)(As + (wm + mt * 16 + ml) * 32 + qd * 8);
#pragma unroll
        for (int nt = 0; nt < 4; ++nt)
            bfv[nt] = *(const half8*)(Bs + (wn + nt * 16 + ml) * 32 + qd * 8);
#pragma unroll
        for (int mt = 0; mt < 4; ++mt)
#pragma unroll
            for (int nt = 0; nt < 4; ++nt)
                acc[mt][nt] = __builtin_amdgcn_mfma_f32_16x16x32_f16(af[mt], bfv[nt], acc[mt][nt], 0, 0, 0);
    }

    // Epilogue. C/D layout: col = lane&15, row = quad*4 + reg.
#pragma unroll
    for (int nt = 0; nt < 4; ++nt) {
        int col = n0 + wn + nt * 16 + ml;
        if (col >= N) continue;
        float bv = bias ? bias[col] : 0.f;
#pragma unroll
        for (int mt = 0; mt < 4; ++mt) {
#pragma unroll
            for (int r = 0; r < 4; ++r) {
                int rowg = m0 + wm + mt * 16 + qd * 4 + r;
                float v = acc[mt][nt][r] * scale + bv;
                if (relu) v = fmaxf(v, 0.f);
                long long off = coff + (long long)rowg * ldc + col;
                if (CF == 1) {
                    ((float*)Cv)[off] = v;
                } else if (CF == 2) {
                    resid[off] = v;
                    ((u16*)Cv)[off] = f2h_bits(v);
                } else if (resid) {
                    float nv = resid[off] + v;
                    resid[off] = nv;
                    ((u16*)Cv)[off] = f2h_bits(nv);
                } else {
                    ((u16*)Cv)[off] = f2h_bits(v);
                }
            }
        }
    }
}

// ---------------------------------------------------------------------------
// Batched transpose into fp16. MODE 0: src already fp16. MODE 1: src raw input.
// R: dst minor-dim bound (iteration); Rs: source row bound (rows >= Rs -> 0).
// ---------------------------------------------------------------------------
template <int MODE>
__global__ void transpose_k(const void* __restrict__ src_, int s_ld, long long s_off,
                            long long s_so, long long s_si,
                            u16* __restrict__ dst, int d_ld, long long d_so, long long d_si,
                            int R, int Rs, int C, const void* caps)
{
    __shared__ u16 tile[32][33];
    const int z = blockIdx.z;
    const long long sb = s_off + (long long)(z >> 3) * s_so + (long long)(z & 7) * s_si;
    dst += (long long)(z >> 3) * d_so + (long long)(z & 7) * d_si;
    const int c0 = blockIdx.x * 32, r0 = blockIdx.y * 32;
    const int tx = threadIdx.x, ty = threadIdx.y;
    const int flag = (MODE == 1) ? detect_bf16(caps) : 0;
#pragma unroll
    for (int i = 0; i < 4; ++i) {
        int r = r0 + ty + i * 8, c = c0 + tx;
        if (r < R && c < C) {
            u16 v = 0;
            if (r < Rs) {
                size_t idx = (size_t)(sb + (long long)r * s_ld + c);
                if (MODE == 1) v = f2h_bits(ldin(src_, idx, flag));
                else           v = ((const u16*)src_)[idx];
            }
            tile[ty + i * 8][tx] = v;
        }
    }
    __syncthreads();
#pragma unroll
    for (int i = 0; i < 4; ++i) {
        int r = r0 + tx, c = c0 + ty + i * 8;
        if (r < R && c < C) dst[(long long)c * d_ld + r] = tile[tx][ty + i * 8];
    }
}

// Fused transpose of Wq/Wk/Wv/Wo (each 512x512 at layer offset oW) -> Bt fp16.
// z = 0..3 selects source; q/k/v -> wqkvT (+z*262144), o -> woT.
__global__ void qkvoT_k(const void* Wq, const void* Wk, const void* Wv, const void* Wo,
                        long long oW, u16* __restrict__ wqkvT, u16* __restrict__ woT,
                        const void* caps)
{
    __shared__ u16 tile[32][33];
    const int z = blockIdx.z;
    const void* src = (z == 0) ? Wq : (z == 1) ? Wk : (z == 2) ? Wv : Wo;
    u16* dst = (z < 3) ? (wqkvT + (long long)z * 262144) : woT;
    const int c0 = blockIdx.x * 32, r0 = blockIdx.y * 32;
    const int tx = threadIdx.x, ty = threadIdx.y;
    const int flag = detect_bf16(caps);
#pragma unroll
    for (int i = 0; i < 4; ++i) {
        int r = r0 + ty + i * 8, c = c0 + tx;
        tile[ty + i * 8][tx] = f2h_bits(ldin(src, (size_t)(oW + (long long)r * 512 + c), flag));
    }
    __syncthreads();
#pragma unroll
    for (int i = 0; i < 4; ++i) {
        int r = r0 + tx, c = c0 + ty + i * 8;
        dst[(long long)c * 512 + r] = tile[tx][ty + i * 8];
    }
}

__global__ void cvt_small_k(const void* srcW, const void* srcB, const void* candW, const void* candB,
                            const void* depW, const void* depB, const void* feasW, const void* feasB,
                            const void* pW, const void* pb, const void* boi, const void* b1i,
                            const void* b2i, const void* caps, float* __restrict__ dst)
{
    int i = blockIdx.x * 256 + threadIdx.x;
    if (i >= A_TOTAL) return;
    int flag = detect_bf16(caps);
    const void* s; int j;
    if      (i < A_SRCB)  { s = srcW;  j = i - A_SRCW; }
    else if (i < A_CANDW) { s = srcB;  j = i - A_SRCB; }
    else if (i < A_CANDB) { s = candW; j = i - A_CANDW; }
    else if (i < A_DEPW)  { s = candB; j = i - A_CANDB; }
    else if (i < A_DEPB)  { s = depW;  j = i - A_DEPW; }
    else if (i < A_FEASW) { s = depB;  j = i - A_DEPB; }
    else if (i < A_FEASB) { s = feasW; j = i - A_FEASW; }
    else if (i < A_PW)    { s = feasB; j = i - A_FEASB; }
    else if (i < A_PB)    { s = pW;    j = i - A_PW; }
    else if (i < A_BO)    { s = pb;    j = i - A_PB; }
    else if (i < A_B1)    { s = boi;   j = i - A_BO; }
    else if (i < A_B2)    { s = b1i;   j = i - A_B1; }
    else                  { s = b2i;   j = i - A_B2; }
    dst[i] = ldin(s, j, flag);
}

__global__ void catbias_k(const void* bq, const void* bk, const void* bv,
                          const void* caps, float* __restrict__ dst)
{
    int t = blockIdx.x * 256 + threadIdx.x;
    if (t >= 6 * 1536) return;
    int flag = detect_bf16(caps);
    int l = t / 1536, j = t - l * 1536;
    float v = (j < 512) ? ldin(bq, l * 512 + j, flag)
            : (j < 1024) ? ldin(bk, l * 512 + j - 512, flag)
                         : ldin(bv, l * 512 + j - 1024, flag);
    dst[t] = v;
}

// Build xin fp16 [4096 x 288]: cols 0..255 = emb[idx], col 256 = nd, 257..287 = 0.
__global__ __launch_bounds__(256) void gather_xin_k(
    const void* __restrict__ sol, const void* __restrict__ caps, const void* __restrict__ emb,
    u16* __restrict__ xin)
{
    const int row = blockIdx.x;
    const int b = row >> 9, s = row & 511;
    const int t = threadIdx.x;
    const int flag = detect_bf16(caps);
    float idxf = ldin(sol, (size_t)row * 4, flag);
    int idx = (int)(idxf + 0.5f);
    if (idx < 0) idx = 0;
    if (idx > 9999) idx = 9999;
    xin[(size_t)row * 288 + t] = f2h_bits(ldin(emb, (size_t)idx * 256 + t, flag));
    if (t < 32) {
        float v = 0.f;
        if (t == 0 && s != 0) {
            float rem = ldin(sol, ((size_t)b * 512) * 4 + 3, flag);
            float cap = ldin(caps, b, flag);
            float dem = ldin(sol, (size_t)row * 4 + 2, flag);
            v = 2.f * (dem - rem) / cap;
        }
        xin[(size_t)row * 288 + 256 + t] = f2h_bits(v);
    }
}

// Recompute the 16 rows (s=0 src, s=511 dep) in fp32 (overwrites enc-gemm values).
__global__ __launch_bounds__(256) void fixup_enc_k(
    const void* __restrict__ sol, const void* __restrict__ caps, const void* __restrict__ emb,
    const float* __restrict__ arena, float* __restrict__ xf, u16* __restrict__ xb)
{
    const int blk = blockIdx.x;
    const int b = blk & 7;
    const int s = (blk >> 3) ? 511 : 0;
    const int row = b * 512 + s;
    const int t = threadIdx.x;
    __shared__ float e[256];
    __shared__ float nds;
    const int flag = detect_bf16(caps);
    float idxf = ldin(sol, (size_t)row * 4, flag);
    int idx = (int)(idxf + 0.5f);
    if (idx < 0) idx = 0;
    if (idx > 9999) idx = 9999;
    e[t] = ldin(emb, (size_t)idx * 256 + t, flag);
    if (t == 0) {
        float rem = ldin(sol, ((size_t)b * 512) * 4 + 3, flag);
        float cap = ldin(caps, b, flag);
        float dem = ldin(sol, (size_t)row * 4 + 2, flag);
        nds = (s == 0) ? 0.f : 2.f * (dem - rem) / cap;
    }
    __syncthreads();
    const float* W  = (s == 0) ? arena + A_SRCW : arena + A_DEPW;
    const float* Bb = (s == 0) ? arena + A_SRCB : arena + A_DEPB;
    float a0 = 0.f, a1 = 0.f;
    for (int c = 0; c < 256; ++c) {
        float ev = e[c];
        a0 += ev * W[(size_t)c * 512 + t];
        a1 += ev * W[(size_t)c * 512 + t + 256];
    }
    float nd = nds;
    a0 += nd * W[256 * 512 + t] + Bb[t];
    a1 += nd * W[256 * 512 + t + 256] + Bb[t + 256];
    size_t o = (size_t)row * 512;
    xf[o + t] = a0;        xb[o + t] = f2h_bits(a0);
    xf[o + t + 256] = a1;  xb[o + t + 256] = f2h_bits(a1);
}

// Row softmax over 512 FP32 scores; writes fp16 WEIGHTS in place (lda=1024 for PV).
// (s_scale*log(n) shift is constant along the softmax axis -> dropped.)
__global__ __launch_bounds__(256) void softmax_k(float* __restrict__ scf)
{
    const int wrow = blockIdx.x * 4 + (threadIdx.x >> 6);
    const int lane = threadIdx.x & 63;
    float* rf = scf + (size_t)wrow * 512;
    float v[8];
    float mx = -3.0e38f;
#pragma unroll
    for (int i = 0; i < 8; ++i) { v[i] = rf[lane + 64 * i]; mx = fmaxf(mx, v[i]); }
#pragma unroll
    for (int o = 1; o < 64; o <<= 1) mx = fmaxf(mx, __shfl_xor(mx, o, 64));
    float s = 0.f;
#pragma unroll
    for (int i = 0; i < 8; ++i) { v[i] = expf(v[i] - mx); s += v[i]; }
#pragma unroll
    for (int o = 1; o < 64; o <<= 1) s += __shfl_xor(s, o, 64);
    float inv = 1.f / s;
    u16* wp = (u16*)rf;
#pragma unroll
    for (int i = 0; i < 8; ++i) wp[lane + 64 * i] = f2h_bits(v[i] * inv);
}

// FFN2 split-K reduce: xf/xb = resid + tmp0 + tmp1 + bias.
__global__ __launch_bounds__(256) void ffn2red_k(const float* __restrict__ tmp,
                                                 const float* __restrict__ bias,
                                                 float* __restrict__ xf, u16* __restrict__ xb)
{
    int i = blockIdx.x * 256 + threadIdx.x;  // 0 .. 4096*512-1
    float v = tmp[i] + tmp[i + 2097152] + bias[i & 511];
    float nv = xf[i] + v;
    xf[i] = nv;
    xb[i] = f2h_bits(nv);
}

// feas head -> FP32 output (d_out is float*)
__global__ __launch_bounds__(256) void feas_k(const float* __restrict__ xf,
                                              const float* __restrict__ arena,
                                              float* __restrict__ out)
{
    int w = blockIdx.x * 4 + (threadIdx.x >> 6);
    if (w >= 8 * 510) return;
    int lane = threadIdx.x & 63;
    int b = w / 510, j = w - b * 510;
    const float* xr = xf + ((size_t)(b * 512 + 1 + j)) * 512;
    const float* fW = arena + A_FEASW;
    float a = 0.f;
#pragma unroll
    for (int i = 0; i < 8; ++i) { int d = lane + 64 * i; a += xr[d] * fW[d]; }
#pragma unroll
    for (int o = 1; o < 64; o <<= 1) a += __shfl_xor(a, o, 64);
    if (lane == 0) out[8160 + b * 510 + j] = a + arena[A_FEASB];
}

// logits head -> FP32 output
__global__ __launch_bounds__(256) void ptr_k(const float* __restrict__ xf,
                                             const float* __restrict__ arena,
                                             float* __restrict__ out)
{
    int w = blockIdx.x * 4 + (threadIdx.x >> 6);
    if (w >= 8 * 510) return;
    int lane = threadIdx.x & 63;
    int b = w / 510, j = w - b * 510;
    const float* xr = xf + ((size_t)(b * 512 + 1 + j)) * 512;
    const float* pWa = arena + A_PW;
    float a0 = 0.f, a1 = 0.f;
#pragma unroll
    for (int i = 0; i < 8; ++i) {
        int d = lane + 64 * i;
        float x = xr[d];
        a0 += x * pWa[d * 2];
        a1 += x * pWa[d * 2 + 1];
    }
#pragma unroll
    for (int o = 1; o < 64; o <<= 1) { a0 += __shfl_xor(a0, o, 64); a1 += __shfl_xor(a1, o, 64); }
    if (lane == 0) {
        out[(size_t)b * 1020 + j]       = a0 + arena[A_PB];
        out[(size_t)b * 1020 + 510 + j] = a1 + arena[A_PB + 1];
    }
}

extern "C" void kernel_launch(void* const* d_in, const int* in_sizes, int n_in,
                              void* d_out, int out_size, void* d_ws, size_t ws_size,
                              hipStream_t stream)
{
    const void* sol   = d_in[0];
    const void* caps  = d_in[1];
    const void* emb   = d_in[2];
    const void* srcW  = d_in[3];
    const void* srcB  = d_in[4];
    const void* candW = d_in[5];
    const void* candB = d_in[6];
    const void* depW  = d_in[7];
    const void* depB  = d_in[8];
    const void* feasW = d_in[9];
    const void* feasB = d_in[10];
    const void* Wq  = d_in[11];
    const void* bq  = d_in[12];
    const void* Wk  = d_in[13];
    const void* bk  = d_in[14];
    const void* Wv  = d_in[15];
    const void* bv  = d_in[16];
    const void* Wo  = d_in[17];
    const void* boi = d_in[18];
    // d_in[19] = s_scale: softmax shift no-op
    const void* W1  = d_in[20];
    const void* b1i = d_in[21];
    const void* W2  = d_in[22];
    const void* b2i = d_in[23];
    const void* pW  = d_in[24];
    const void* pb  = d_in[25];
    float* out = (float*)d_out;

    // workspace (~55.7 MiB; same footprint as passing round 7)
    char* w = (char*)d_ws;
    float* xf    = (float*)w; w += 8388608;   // 4096x512 fp32 residual master
    u16* xb      = (u16*)w;   w += 4194304;   // 4096x512 fp16
    u16* qkvb    = (u16*)w;   w += 12582912;  // 4096x1536 fp16 (q|k|v)
    u16* vt      = (u16*)w;   w += 4194304;   // 64x64x512 fp16 (v^T per head)
    float* scf   = (float*)w; w += 16777216;  // 16x512x512 fp32 scores (quarter)
    u16* hb      = (u16*)scf;                 //  ALIAS: 4096x2048 fp16 FFN hidden
    u16* xin     = (u16*)scf;                 //  ALIAS: 4096x288 fp16 encoder input
    u16* encW    = (u16*)scf + 4096 * 288;    //  ALIAS: 512x288 fp16 candW^T
    float* tmp2  = (float*)qkvb;              //  ALIAS: 2x(4096x512) fp32 FFN2 split-K partials (qkvb+vt)
    u16* ob      = (u16*)w;   w += 4194304;   // 4096x512 fp16 attention out
    u16* wqkvT   = (u16*)w;   w += 1572864;   // 1536x512 fp16 (per-layer)
    u16* woT     = (u16*)w;   w += 524288;    // 512x512 fp16  (per-layer)
    u16* w1T     = (u16*)w;   w += 2097152;   // 2048x512 fp16 (per-layer)
    u16* w2T     = (u16*)w;   w += 2097152;   // 512x2048 fp16 (per-layer)
    float* bqkvf = (float*)w; w += 36864;     // 6x1536 fp32
    float* arena = (float*)w; w += A_TOTAL * 4;

    dim3 tb(32, 8);
    cvt_small_k<<<dim3((A_TOTAL + 255) / 256), 256, 0, stream>>>(
        srcW, srcB, candW, candB, depW, depB, feasW, feasB, pW, pb, boi, b1i, b2i, caps, arena);
    catbias_k<<<dim3(36), 256, 0, stream>>>(bq, bk, bv, caps, bqkvf);

    // Encoder via MFMA: xin [4096x288] @ candW^T [512x288] -> xf/xb, then fixup 16 rows.
    gather_xin_k<<<dim3(4096), 256, 0, stream>>>(sol, caps, emb, xin);
    transpose_k<1><<<dim3(16, 9, 1), tb, 0, stream>>>(candW, 512, 0, 0, 0,
                                                      encW, 288, 0, 0, 288, 257, 512, caps);
    gemm_f16<2><<<dim3(4, 32, 1), 256, 0, stream>>>(
        xin, 288, 0, 0, encW, 288, 0, 0,
        xb, 512, 0, 0, arena + A_CANDB, xf, 1.f, 0, 512, 288);
    fixup_enc_k<<<dim3(16), 256, 0, stream>>>(sol, caps, emb, arena, xf, xb);

    for (int i = 0; i < 6; ++i) {
        const long long oW = (long long)i * 262144, oF = (long long)i * 1048576;
        qkvoT_k<<<dim3(16, 16, 4), tb, 0, stream>>>(Wq, Wk, Wv, Wo, oW, wqkvT, woT, caps);
        transpose_k<1><<<dim3(64, 16, 1), tb, 0, stream>>>(W1, 2048, oF, 0, 0, w1T, 512, 0, 0, 512, 512, 2048, caps);
        transpose_k<1><<<dim3(16, 64, 1), tb, 0, stream>>>(W2, 512, oF, 0, 0, w2T, 2048, 0, 0, 2048, 2048, 512, caps);

        // QKV fused: [4096,512] @ [512,1536]
        gemm_f16<0><<<dim3(12, 32, 1), 256, 0, stream>>>(
            xb, 512, 0, 0, wqkvT, 512, 0, 0,
            qkvb, 1536, 0, 0, bqkvf + i * 1536, nullptr, 1.f, 0, 1536, 512);
        // v^T per (b,h)
        transpose_k<0><<<dim3(2, 16, 64), tb, 0, stream>>>(
            qkvb + 1024, 1536, 0, 786432, 64, vt, 512, 262144, 32768, 512, 512, 64, caps);

        for (int q4 = 0; q4 < 4; ++q4) {  // attention in batch-quarters (2 b x 8 h)
            const long long b2_ = 2LL * q4;
            gemm_f16<1><<<dim3(4, 4, 16), 256, 0, stream>>>(
                qkvb + b2_ * 786432, 1536, 786432, 64, qkvb + b2_ * 786432 + 512, 1536, 786432, 64,
                scf, 512, 2097152, 262144, nullptr, nullptr, 0.125f, 0, 512, 64);
            softmax_k<<<dim3(2048), 256, 0, stream>>>(scf);
            gemm_f16<0><<<dim3(1, 4, 16), 256, 0, stream>>>(
                (u16*)scf, 1024, 4194304, 524288, vt + b2_ * 262144, 512, 262144, 32768,
                ob + b2_ * 262144, 512, 262144, 64, nullptr, nullptr, 1.f, 0, 64, 512);
        }
        // O-proj + residual (qkvb/vt become dead after this point in the layer)
        gemm_f16<0><<<dim3(4, 32, 1), 256, 0, stream>>>(
            ob, 512, 0, 0, woT, 512, 0, 0,
            xb, 512, 0, 0, arena + A_BO + i * 512, xf, 1.f, 0, 512, 512);
        if (i == 0)
            feas_k<<<dim3(1020), 256, 0, stream>>>(xf, arena, out);
        // FFN1 (relu); hb aliases scf
        gemm_f16<0><<<dim3(16, 32, 1), 256, 0, stream>>>(
            xb, 512, 0, 0, w1T, 512, 0, 0,
            hb, 2048, 0, 0, arena + A_B1 + i * 2048, nullptr, 1.f, 1, 2048, 512);
        // FFN2 split-K x2 (z=2, 256 blocks) -> fp32 partials in tmp2, then reduce.
        gemm_f16<1><<<dim3(4, 32, 2), 256, 0, stream>>>(
            hb, 2048, 0, 1024, w2T, 2048, 0, 1024,
            tmp2, 512, 0, 2097152, nullptr, nullptr, 1.f, 0, 512, 1024);
        ffn2red_k<<<dim3(8192), 256, 0, stream>>>(tmp2, arena + A_B2 + i * 512, xf, xb);
    }
    ptr_k<<<dim3(1020), 256, 0, stream>>>(xf, arena, out);
}

// Round 9
// 1245.395 us; speedup vs baseline: 9.5487x; 1.4465x over previous
//
#include <hip/hip_runtime.h>

typedef unsigned short u16;
typedef _Float16 half8 __attribute__((ext_vector_type(8)));
typedef float f32x4 __attribute__((ext_vector_type(4)));

__device__ inline float bf2f(u16 b) { return __builtin_bit_cast(float, ((unsigned)b) << 16); }
__device__ inline float h2f(u16 h) { return (float)__builtin_bit_cast(_Float16, h); }
__device__ inline u16 f2h_bits(float f) { return __builtin_bit_cast(u16, (_Float16)f); }

__device__ inline int detect_bf16(const void* caps) {
    const u16* c = (const u16*)caps;
    int cnt = 0;
#pragma unroll
    for (int k = 0; k < 4; ++k) {
        float v = bf2f(c[2 * k]);
        if (v >= 20.f && v <= 200.f) cnt++;
    }
    return cnt >= 2;
}
__device__ inline float ldin(const void* p, size_t i, int flag) {
    return flag ? bf2f(((const u16*)p)[i]) : ((const float*)p)[i];
}

#define GLOAD_LDS16(g, l)                                                              \
    __builtin_amdgcn_global_load_lds((__attribute__((address_space(1))) const void*)(g), \
                                     (__attribute__((address_space(3))) void*)(l), 16, 0, 0)

#define A_SRCW 0
#define A_SRCB 131584
#define A_CANDW 132096
#define A_CANDB 263680
#define A_DEPW 264192
#define A_DEPB 395776
#define A_FEASW 396288
#define A_FEASB 396800
#define A_PW 396801
#define A_PB 397825
#define A_BO 397827
#define A_B1 400899
#define A_B2 413187
#define A_TOTAL 416259

template <int CF>
__global__ __launch_bounds__(256) void gemm_f16(
    const u16* __restrict__ A, int lda, long long a_so, long long a_si,
    const u16* __restrict__ B, int ldb, long long b_so, long long b_si,
    void* __restrict__ Cv, int ldc, long long c_so, long long c_si,
    const float* __restrict__ bias, float* __restrict__ resid,
    float scale, int relu, int N, int K)
{
    __shared__ __attribute__((aligned(16))) u16 As[128 * 32];
    __shared__ __attribute__((aligned(16))) u16 Bs[128 * 32];

    const int z = blockIdx.z;
    A += (long long)(z >> 3) * a_so + (long long)(z & 7) * a_si;
    B += (long long)(z >> 3) * b_so + (long long)(z & 7) * b_si;
    const long long coff = (long long)(z >> 3) * c_so + (long long)(z & 7) * c_si;

    const int m0 = blockIdx.y * 128;
    const int n0 = blockIdx.x * 128;
    const int t = threadIdx.x, lane = t & 63, wid = t >> 6;
    const int qd = lane >> 4, ml = lane & 15;
    const int wm = (wid >> 1) * 64, wn = (wid & 1) * 64;

    f32x4 acc[4][4] = {};

    for (int k0 = 0; k0 < K; k0 += 32) {
        __syncthreads();
#pragma unroll
        for (int rep = 0; rep < 2; ++rep) {
            int seg = (wid + rep * 4) * 64 + lane;
            int row = seg >> 2, c8 = (seg & 3) * 8;
            const u16* ga = A + (long long)(m0 + row) * lda + k0 + c8;
            GLOAD_LDS16(ga, As + (size_t)(seg & ~63) * 8);
            int rn = n0 + row;
            if (rn > N - 1) rn = N - 1;
            const u16* gb = B + (long long)rn * ldb + k0 + c8;
            GLOAD_LDS16(gb, Bs + (size_t)(seg & ~63) * 8);
        }
        __syncthreads();

        half8 af[4], bfv[4];
#pragma unroll
        for (int mt = 0; mt < 4; ++mt)
            af[mt] = *(const half8*)(As + (wm + mt * 16 + ml) * 32 + qd * 8);
#pragma unroll
        for (int nt = 0; nt < 4; ++nt)
            bfv[nt] = *(const half8*)(Bs + (wn + nt * 16 + ml) * 32 + qd * 8);
#pragma unroll
        for (int mt = 0; mt < 4; ++mt)
#pragma unroll
            for (int nt = 0; nt < 4; ++nt)
                acc[mt][nt] = __builtin_amdgcn_mfma_f32_16x16x32_f16(af[mt], bfv[nt], acc[mt][nt], 0, 0, 0);
    }

#pragma unroll
    for (int nt = 0; nt < 4; ++nt) {
        int col = n0 + wn + nt * 16 + ml;
        if (col >= N) continue;
        float bv = bias ? bias[col] : 0.f;
#pragma unroll
        for (int mt = 0; mt < 4; ++mt) {
#pragma unroll
            for (int r = 0; r < 4; ++r) {
                int rowg = m0 + wm + mt * 16 + qd * 4 + r;
                float v = acc[mt][nt][r] * scale + bv;
                if (relu) v = fmaxf(v, 0.f);
                long long off = coff + (long long)rowg * ldc + col;
                if (CF == 1) {
                    ((float*)Cv)[off] = v;
                } else if (CF == 2) {
                    resid[off] = v;
                    ((u16*)Cv)[off] = f2h_bits(v);
                } else if (resid) {
                    float nv = resid[off] + v;
                    resid[off] = nv;
                    ((u16*)Cv)[off] = f2h_bits(nv);
                } else {
                    ((u16*)Cv)[off] = f2h_bits(v);
                }
            }
        }
    }
}

template <int MODE>
__global__ void transpose_k(const void* __restrict__ src_, int s_ld, long long s_off,
                            long long s_so, long long s_si,
                            u16* __restrict__ dst, int d_ld, long long d_so, long long d_si,
                            int R, int Rs, int C, const void* caps)
{
    __shared__ u16 tile[32][33];
    const int z = blockIdx.z;
    const long long sb = s_off + (long long)(z >> 3) * s_so + (long long)(z & 7) * s_si;
    dst += (long long)(z >> 3) * d_so + (long long)(z & 7) * d_si;
    const int c0 = blockIdx.x * 32, r0 = blockIdx.y * 32;
    const int tx = threadIdx.x, ty = threadIdx.y;
    const int flag = (MODE == 1) ? detect_bf16(caps) : 0;
#pragma unroll
    for (int i = 0; i < 4; ++i) {
        int r = r0 + ty + i * 8, c = c0 + tx;
        if (r < R && c < C) {
            u16 v = 0;
            if (r < Rs) {
                size_t idx = (size_t)(sb + (long long)r * s_ld + c);
                if (MODE == 1) v = f2h_bits(ldin(src_, idx, flag));
                else           v = ((const u16*)src_)[idx];
            }
            tile[ty + i * 8][tx] = v;
        }
    }
    __syncthreads();
#pragma unroll
    for (int i = 0; i < 4; ++i) {
        int r = r0 + tx, c = c0 + ty + i * 8;
        if (r < R && c < C) dst[(long long)c * d_ld + r] = tile[tx][ty + i * 8];
    }
}

// All 6 layers' Wq/Wk/Wv/Wo transposes in one dispatch.
// z = layer*4 + sel; sel 0..2 -> wqkvT6[layer](+sel*262144), sel 3 -> woT6[layer].
__global__ void qkvoT6_k(const void* Wq, const void* Wk, const void* Wv, const void* Wo,
                         u16* __restrict__ wqkvT6, u16* __restrict__ woT6,
                         const void* caps)
{
    __shared__ u16 tile[32][33];
    const int z = blockIdx.z;
    const int layer = z >> 2, sel = z & 3;
    const void* src = (sel == 0) ? Wq : (sel == 1) ? Wk : (sel == 2) ? Wv : Wo;
    u16* dst = (sel < 3) ? (wqkvT6 + (long long)layer * 786432 + (long long)sel * 262144)
                         : (woT6 + (long long)layer * 262144);
    const long long oW = (long long)layer * 262144;
    const int c0 = blockIdx.x * 32, r0 = blockIdx.y * 32;
    const int tx = threadIdx.x, ty = threadIdx.y;
    const int flag = detect_bf16(caps);
#pragma unroll
    for (int i = 0; i < 4; ++i) {
        int r = r0 + ty + i * 8, c = c0 + tx;
        tile[ty + i * 8][tx] = f2h_bits(ldin(src, (size_t)(oW + (long long)r * 512 + c), flag));
    }
    __syncthreads();
#pragma unroll
    for (int i = 0; i < 4; ++i) {
        int r = r0 + tx, c = c0 + ty + i * 8;
        dst[(long long)c * 512 + r] = tile[tx][ty + i * 8];
    }
}

__global__ void cvt_small_k(const void* srcW, const void* srcB, const void* candW, const void* candB,
                            const void* depW, const void* depB, const void* feasW, const void* feasB,
                            const void* pW, const void* pb, const void* boi, const void* b1i,
                            const void* b2i, const void* caps, float* __restrict__ dst)
{
    int i = blockIdx.x * 256 + threadIdx.x;
    if (i >= A_TOTAL) return;
    int flag = detect_bf16(caps);
    const void* s; int j;
    if      (i < A_SRCB)  { s = srcW;  j = i - A_SRCW; }
    else if (i < A_CANDW) { s = srcB;  j = i - A_SRCB; }
    else if (i < A_CANDB) { s = candW; j = i - A_CANDW; }
    else if (i < A_DEPW)  { s = candB; j = i - A_CANDB; }
    else if (i < A_DEPB)  { s = depW;  j = i - A_DEPW; }
    else if (i < A_FEASW) { s = depB;  j = i - A_DEPB; }
    else if (i < A_FEASB) { s = feasW; j = i - A_FEASW; }
    else if (i < A_PW)    { s = feasB; j = i - A_FEASB; }
    else if (i < A_PB)    { s = pW;    j = i - A_PW; }
    else if (i < A_BO)    { s = pb;    j = i - A_PB; }
    else if (i < A_B1)    { s = boi;   j = i - A_BO; }
    else if (i < A_B2)    { s = b1i;   j = i - A_B1; }
    else                  { s = b2i;   j = i - A_B2; }
    dst[i] = ldin(s, j, flag);
}

__global__ void catbias_k(const void* bq, const void* bk, const void* bv,
                          const void* caps, float* __restrict__ dst)
{
    int t = blockIdx.x * 256 + threadIdx.x;
    if (t >= 6 * 1536) return;
    int flag = detect_bf16(caps);
    int l = t / 1536, j = t - l * 1536;
    float v = (j < 512) ? ldin(bq, l * 512 + j, flag)
            : (j < 1024) ? ldin(bk, l * 512 + j - 512, flag)
                         : ldin(bv, l * 512 + j - 1024, flag);
    dst[t] = v;
}

__global__ __launch_bounds__(256) void gather_xin_k(
    const void* __restrict__ sol, const void* __restrict__ caps, const void* __restrict__ emb,
    u16* __restrict__ xin)
{
    const int row = blockIdx.x;
    const int b = row >> 9, s = row & 511;
    const int t = threadIdx.x;
    const int flag = detect_bf16(caps);
    float idxf = ldin(sol, (size_t)row * 4, flag);
    int idx = (int)(idxf + 0.5f);
    if (idx < 0) idx = 0;
    if (idx > 9999) idx = 9999;
    xin[(size_t)row * 288 + t] = f2h_bits(ldin(emb, (size_t)idx * 256 + t, flag));
    if (t < 32) {
        float v = 0.f;
        if (t == 0 && s != 0) {
            float rem = ldin(sol, ((size_t)b * 512) * 4 + 3, flag);
            float cap = ldin(caps, b, flag);
            float dem = ldin(sol, (size_t)row * 4 + 2, flag);
            v = 2.f * (dem - rem) / cap;
        }
        xin[(size_t)row * 288 + 256 + t] = f2h_bits(v);
    }
}

__global__ __launch_bounds__(256) void fixup_enc_k(
    const void* __restrict__ sol, const void* __restrict__ caps, const void* __restrict__ emb,
    const float* __restrict__ arena, float* __restrict__ xf, u16* __restrict__ xb)
{
    const int blk = blockIdx.x;
    const int b = blk & 7;
    const int s = (blk >> 3) ? 511 : 0;
    const int row = b * 512 + s;
    const int t = threadIdx.x;
    __shared__ float e[256];
    __shared__ float nds;
    const int flag = detect_bf16(caps);
    float idxf = ldin(sol, (size_t)row * 4, flag);
    int idx = (int)(idxf + 0.5f);
    if (idx < 0) idx = 0;
    if (idx > 9999) idx = 9999;
    e[t] = ldin(emb, (size_t)idx * 256 + t, flag);
    if (t == 0) {
        float rem = ldin(sol, ((size_t)b * 512) * 4 + 3, flag);
        float cap = ldin(caps, b, flag);
        float dem = ldin(sol, (size_t)row * 4 + 2, flag);
        nds = (s == 0) ? 0.f : 2.f * (dem - rem) / cap;
    }
    __syncthreads();
    const float* W  = (s == 0) ? arena + A_SRCW : arena + A_DEPW;
    const float* Bb = (s == 0) ? arena + A_SRCB : arena + A_DEPB;
    float a0 = 0.f, a1 = 0.f;
    for (int c = 0; c < 256; ++c) {
        float ev = e[c];
        a0 += ev * W[(size_t)c * 512 + t];
        a1 += ev * W[(size_t)c * 512 + t + 256];
    }
    float nd = nds;
    a0 += nd * W[256 * 512 + t] + Bb[t];
    a1 += nd * W[256 * 512 + t + 256] + Bb[t + 256];
    size_t o = (size_t)row * 512;
    xf[o + t] = a0;        xb[o + t] = f2h_bits(a0);
    xf[o + t + 256] = a1;  xb[o + t + 256] = f2h_bits(a1);
}

__global__ __launch_bounds__(256) void softmax_k(float* __restrict__ scf)
{
    const int wrow = blockIdx.x * 4 + (threadIdx.x >> 6);
    const int lane = threadIdx.x & 63;
    float* rf = scf + (size_t)wrow * 512;
    float v[8];
    float mx = -3.0e38f;
#pragma unroll
    for (int i = 0; i < 8; ++i) { v[i] = rf[lane + 64 * i]; mx = fmaxf(mx, v[i]); }
#pragma unroll
    for (int o = 1; o < 64; o <<= 1) mx = fmaxf(mx, __shfl_xor(mx, o, 64));
    float s = 0.f;
#pragma unroll
    for (int i = 0; i < 8; ++i) { v[i] = expf(v[i] - mx); s += v[i]; }
#pragma unroll
    for (int o = 1; o < 64; o <<= 1) s += __shfl_xor(s, o, 64);
    float inv = 1.f / s;
    u16* wp = (u16*)rf;
#pragma unroll
    for (int i = 0; i < 8; ++i) wp[lane + 64 * i] = f2h_bits(v[i] * inv);
}

__global__ __launch_bounds__(256) void ffn2red_k(const float* __restrict__ tmp,
                                                 const float* __restrict__ bias,
                                                 float* __restrict__ xf, u16* __restrict__ xb)
{
    int i = blockIdx.x * 256 + threadIdx.x;
    float v = tmp[i] + tmp[i + 2097152] + bias[i & 511];
    float nv = xf[i] + v;
    xf[i] = nv;
    xb[i] = f2h_bits(nv);
}

__global__ __launch_bounds__(256) void feas_k(const float* __restrict__ xf,
                                              const float* __restrict__ arena,
                                              float* __restrict__ out)
{
    int w = blockIdx.x * 4 + (threadIdx.x >> 6);
    if (w >= 8 * 510) return;
    int lane = threadIdx.x & 63;
    int b = w / 510, j = w - b * 510;
    const float* xr = xf + ((size_t)(b * 512 + 1 + j)) * 512;
    const float* fW = arena + A_FEASW;
    float a = 0.f;
#pragma unroll
    for (int i = 0; i < 8; ++i) { int d = lane + 64 * i; a += xr[d] * fW[d]; }
#pragma unroll
    for (int o = 1; o < 64; o <<= 1) a += __shfl_xor(a, o, 64);
    if (lane == 0) out[8160 + b * 510 + j] = a + arena[A_FEASB];
}

__global__ __launch_bounds__(256) void ptr_k(const float* __restrict__ xf,
                                             const float* __restrict__ arena,
                                             float* __restrict__ out)
{
    int w = blockIdx.x * 4 + (threadIdx.x >> 6);
    if (w >= 8 * 510) return;
    int lane = threadIdx.x & 63;
    int b = w / 510, j = w - b * 510;
    const float* xr = xf + ((size_t)(b * 512 + 1 + j)) * 512;
    const float* pWa = arena + A_PW;
    float a0 = 0.f, a1 = 0.f;
#pragma unroll
    for (int i = 0; i < 8; ++i) {
        int d = lane + 64 * i;
        float x = xr[d];
        a0 += x * pWa[d * 2];
        a1 += x * pWa[d * 2 + 1];
    }
#pragma unroll
    for (int o = 1; o < 64; o <<= 1) { a0 += __shfl_xor(a0, o, 64); a1 += __shfl_xor(a1, o, 64); }
    if (lane == 0) {
        out[(size_t)b * 1020 + j]       = a0 + arena[A_PB];
        out[(size_t)b * 1020 + 510 + j] = a1 + arena[A_PB + 1];
    }
}

extern "C" void kernel_launch(void* const* d_in, const int* in_sizes, int n_in,
                              void* d_out, int out_size, void* d_ws, size_t ws_size,
                              hipStream_t stream)
{
    const void* sol   = d_in[0];
    const void* caps  = d_in[1];
    const void* emb   = d_in[2];
    const void* srcW  = d_in[3];
    const void* srcB  = d_in[4];
    const void* candW = d_in[5];
    const void* candB = d_in[6];
    const void* depW  = d_in[7];
    const void* depB  = d_in[8];
    const void* feasW = d_in[9];
    const void* feasB = d_in[10];
    const void* Wq  = d_in[11];
    const void* bq  = d_in[12];
    const void* Wk  = d_in[13];
    const void* bk  = d_in[14];
    const void* Wv  = d_in[15];
    const void* bv  = d_in[16];
    const void* Wo  = d_in[17];
    const void* boi = d_in[18];
    // d_in[19] = s_scale: softmax shift no-op
    const void* W1  = d_in[20];
    const void* b1i = d_in[21];
    const void* W2  = d_in[22];
    const void* b2i = d_in[23];
    const void* pW  = d_in[24];
    const void* pb  = d_in[25];
    float* out = (float*)d_out;

    // workspace (~134 MiB of 256 MiB)
    char* w = (char*)d_ws;
    float* xf    = (float*)w; w += 8388608;   // 4096x512 fp32 residual master
    u16* xb      = (u16*)w;   w += 4194304;   // 4096x512 fp16
    u16* qkvb    = (u16*)w;   w += 12582912;  // 4096x1536 fp16 (q|k|v)
    u16* vt      = (u16*)w;   w += 4194304;   // 64x64x512 fp16 (v^T per head)
    float* scf   = (float*)w; w += 67108864;  // 64x512x512 fp32 scores (FULL batch)
    u16* hb      = (u16*)scf;                 //  ALIAS: FFN hidden
    u16* xin     = (u16*)scf;                 //  ALIAS: encoder input
    u16* encW    = (u16*)scf + 4096 * 288;    //  ALIAS: candW^T fp16
    float* tmp2  = (float*)qkvb;              //  ALIAS: FFN2 split-K partials (qkvb+vt, 16 MB)
    u16* ob      = (u16*)w;   w += 4194304;   // 4096x512 fp16 attention out
    u16* wqkvT6  = (u16*)w;   w += 9437184;   // 6x 1536x512 fp16
    u16* woT6    = (u16*)w;   w += 3145728;   // 6x 512x512 fp16
    u16* w1T6    = (u16*)w;   w += 12582912;  // 6x 2048x512 fp16
    u16* w2T6    = (u16*)w;   w += 12582912;  // 6x 512x2048 fp16
    float* bqkvf = (float*)w; w += 36864;     // 6x1536 fp32
    float* arena = (float*)w; w += A_TOTAL * 4;

    dim3 tb(32, 8);
    cvt_small_k<<<dim3((A_TOTAL + 255) / 256), 256, 0, stream>>>(
        srcW, srcB, candW, candB, depW, depB, feasW, feasB, pW, pb, boi, b1i, b2i, caps, arena);
    catbias_k<<<dim3(36), 256, 0, stream>>>(bq, bk, bv, caps, bqkvf);

    // All weight transposes hoisted out of the layer loop (3 dispatches).
    qkvoT6_k<<<dim3(16, 16, 24), tb, 0, stream>>>(Wq, Wk, Wv, Wo, wqkvT6, woT6, caps);
    transpose_k<1><<<dim3(64, 16, 6), tb, 0, stream>>>(W1, 2048, 0, 0, 1048576,
                                                       w1T6, 512, 0, 1048576, 512, 512, 2048, caps);
    transpose_k<1><<<dim3(16, 64, 6), tb, 0, stream>>>(W2, 512, 0, 0, 1048576,
                                                       w2T6, 2048, 0, 1048576, 2048, 2048, 512, caps);

    // Encoder via MFMA + 16-row fixup.
    gather_xin_k<<<dim3(4096), 256, 0, stream>>>(sol, caps, emb, xin);
    transpose_k<1><<<dim3(16, 9, 1), tb, 0, stream>>>(candW, 512, 0, 0, 0,
                                                      encW, 288, 0, 0, 288, 257, 512, caps);
    gemm_f16<2><<<dim3(4, 32, 1), 256, 0, stream>>>(
        xin, 288, 0, 0, encW, 288, 0, 0,
        xb, 512, 0, 0, arena + A_CANDB, xf, 1.f, 0, 512, 288);
    fixup_enc_k<<<dim3(16), 256, 0, stream>>>(sol, caps, emb, arena, xf, xb);

    for (int i = 0; i < 6; ++i) {
        gemm_f16<0><<<dim3(12, 32, 1), 256, 0, stream>>>(
            xb, 512, 0, 0, wqkvT6 + (long long)i * 786432, 512, 0, 0,
            qkvb, 1536, 0, 0, bqkvf + i * 1536, nullptr, 1.f, 0, 1536, 512);
        transpose_k<0><<<dim3(2, 16, 64), tb, 0, stream>>>(
            qkvb + 1024, 1536, 0, 786432, 64, vt, 512, 262144, 32768, 512, 512, 64, caps);

        // Full-batch attention (z=64): scores -> softmax -> PV.
        gemm_f16<1><<<dim3(4, 4, 64), 256, 0, stream>>>(
            qkvb, 1536, 786432, 64, qkvb + 512, 1536, 786432, 64,
            scf, 512, 2097152, 262144, nullptr, nullptr, 0.125f, 0, 512, 64);
        softmax_k<<<dim3(8192), 256, 0, stream>>>(scf);
        gemm_f16<0><<<dim3(1, 4, 64), 256, 0, stream>>>(
            (u16*)scf, 1024, 4194304, 524288, vt, 512, 262144, 32768,
            ob, 512, 262144, 64, nullptr, nullptr, 1.f, 0, 64, 512);

        gemm_f16<0><<<dim3(4, 32, 1), 256, 0, stream>>>(
            ob, 512, 0, 0, woT6 + (long long)i * 262144, 512, 0, 0,
            xb, 512, 0, 0, arena + A_BO + i * 512, xf, 1.f, 0, 512, 512);
        if (i == 0)
            feas_k<<<dim3(1020), 256, 0, stream>>>(xf, arena, out);
        gemm_f16<0><<<dim3(16, 32, 1), 256, 0, stream>>>(
            xb, 512, 0, 0, w1T6 + (long long)i * 1048576, 512, 0, 0,
            hb, 2048, 0, 0, arena + A_B1 + i * 2048, nullptr, 1.f, 1, 2048, 512);
        gemm_f16<1><<<dim3(4, 32, 2), 256, 0, stream>>>(
            hb, 2048, 0, 1024, w2T6 + (long long)i * 1048576, 2048, 0, 1024,
            tmp2, 512, 0, 2097152, nullptr, nullptr, 1.f, 0, 512, 1024);
        ffn2red_k<<<dim3(8192), 256, 0, stream>>>(tmp2, arena + A_B2 + i * 512, xf, xb);
    }
    ptr_k<<<dim3(1020), 256, 0, stream>>>(xf, arena, out);
}

// Round 10
// 1083.262 us; speedup vs baseline: 10.9779x; 1.1497x over previous
//
#include <hip/hip_runtime.h>

typedef unsigned short u16;
typedef _Float16 half8 __attribute__((ext_vector_type(8)));
typedef float f32x4 __attribute__((ext_vector_type(4)));

__device__ inline float bf2f(u16 b) { return __builtin_bit_cast(float, ((unsigned)b) << 16); }
__device__ inline float h2f(u16 h) { return (float)__builtin_bit_cast(_Float16, h); }
__device__ inline u16 f2h_bits(float f) { return __builtin_bit_cast(u16, (_Float16)f); }

__device__ inline int detect_bf16(const void* caps) {
    const u16* c = (const u16*)caps;
    int cnt = 0;
#pragma unroll
    for (int k = 0; k < 4; ++k) {
        float v = bf2f(c[2 * k]);
        if (v >= 20.f && v <= 200.f) cnt++;
    }
    return cnt >= 2;
}
__device__ inline float ldin(const void* p, size_t i, int flag) {
    return flag ? bf2f(((const u16*)p)[i]) : ((const float*)p)[i];
}

#define GLOAD_LDS16(g, l)                                                              \
    __builtin_amdgcn_global_load_lds((__attribute__((address_space(1))) const void*)(g), \
                                     (__attribute__((address_space(3))) void*)(l), 16, 0, 0)

#define A_SRCW 0
#define A_SRCB 131584
#define A_CANDW 132096
#define A_CANDB 263680
#define A_DEPW 264192
#define A_DEPB 395776
#define A_FEASW 396288
#define A_FEASB 396800
#define A_PW 396801
#define A_PB 397825
#define A_BO 397827
#define A_B1 400899
#define A_B2 413187
#define A_TOTAL 416259

template <int CF>
__global__ __launch_bounds__(256) void gemm_f16(
    const u16* __restrict__ A, int lda, long long a_so, long long a_si,
    const u16* __restrict__ B, int ldb, long long b_so, long long b_si,
    void* __restrict__ Cv, int ldc, long long c_so, long long c_si,
    const float* __restrict__ bias, float* __restrict__ resid,
    float scale, int relu, int N, int K)
{
    __shared__ __attribute__((aligned(16))) u16 As[128 * 32];
    __shared__ __attribute__((aligned(16))) u16 Bs[128 * 32];

    const int z = blockIdx.z;
    A += (long long)(z >> 3) * a_so + (long long)(z & 7) * a_si;
    B += (long long)(z >> 3) * b_so + (long long)(z & 7) * b_si;
    const long long coff = (long long)(z >> 3) * c_so + (long long)(z & 7) * c_si;

    const int m0 = blockIdx.y * 128;
    const int n0 = blockIdx.x * 128;
    const int t = threadIdx.x, lane = t & 63, wid = t >> 6;
    const int qd = lane >> 4, ml = lane & 15;
    const int wm = (wid >> 1) * 64, wn = (wid & 1) * 64;

    f32x4 acc[4][4] = {};

    for (int k0 = 0; k0 < K; k0 += 32) {
        __syncthreads();
#pragma unroll
        for (int rep = 0; rep < 2; ++rep) {
            int seg = (wid + rep * 4) * 64 + lane;
            int row = seg >> 2, c8 = (seg & 3) * 8;
            const u16* ga = A + (long long)(m0 + row) * lda + k0 + c8;
            GLOAD_LDS16(ga, As + (size_t)(seg & ~63) * 8);
            int rn = n0 + row;
            if (rn > N - 1) rn = N - 1;
            const u16* gb = B + (long long)rn * ldb + k0 + c8;
            GLOAD_LDS16(gb, Bs + (size_t)(seg & ~63) * 8);
        }
        __syncthreads();

        half8 af[4], bfv[4];
#pragma unroll
        for (int mt = 0; mt < 4; ++mt)
            af[mt] = *(const half8*)(As + (wm + mt * 16 + ml) * 32 + qd * 8);
#pragma unroll
        for (int nt = 0; nt < 4; ++nt)
            bfv[nt] = *(const half8*)(Bs + (wn + nt * 16 + ml) * 32 + qd * 8);
#pragma unroll
        for (int mt = 0; mt < 4; ++mt)
#pragma unroll
            for (int nt = 0; nt < 4; ++nt)
                acc[mt][nt] = __builtin_amdgcn_mfma_f32_16x16x32_f16(af[mt], bfv[nt], acc[mt][nt], 0, 0, 0);
    }

#pragma unroll
    for (int nt = 0; nt < 4; ++nt) {
        int col = n0 + wn + nt * 16 + ml;
        if (col >= N) continue;
        float bv = bias ? bias[col] : 0.f;
#pragma unroll
        for (int mt = 0; mt < 4; ++mt) {
#pragma unroll
            for (int r = 0; r < 4; ++r) {
                int rowg = m0 + wm + mt * 16 + qd * 4 + r;
                float v = acc[mt][nt][r] * scale + bv;
                if (relu) v = fmaxf(v, 0.f);
                long long off = coff + (long long)rowg * ldc + col;
                if (CF == 1) {
                    ((float*)Cv)[off] = v;
                } else if (CF == 2) {
                    resid[off] = v;
                    ((u16*)Cv)[off] = f2h_bits(v);
                } else if (resid) {
                    float nv = resid[off] + v;
                    resid[off] = nv;
                    ((u16*)Cv)[off] = f2h_bits(nv);
                } else {
                    ((u16*)Cv)[off] = f2h_bits(v);
                }
            }
        }
    }
}

// ---------------------------------------------------------------------------
// Fused flash attention: per (q-tile, b*8+h) block computes
// O = softmax(Q K^T / 8) V using HW-verified MFMA fragment layouts.
// grid (4, 64); 4 waves x 32 Q-rows. K/V frags from L2-hot global; P via
// per-wave-private LDS slab (NO barriers anywhere). Online softmax fp32.
// ---------------------------------------------------------------------------
__global__ __launch_bounds__(256) void flash_k(
    const u16* __restrict__ qkv,  // [4096][1536] fp16 (q|k|v)
    const u16* __restrict__ vt,   // [64][64][512] fp16  v^T per slice
    u16* __restrict__ ob)         // [4096][512] fp16
{
    __shared__ __attribute__((aligned(16))) u16 Ps[128 * 136];  // pad 136: 16B-aligned rows, no bank conflicts

    const int z = blockIdx.y;  // b*8 + h
    const int b = z >> 3, h = z & 7;
    const int q0 = blockIdx.x * 128;
    const long long qbase = (long long)b * 786432;
    const u16* Q  = qkv + qbase + (long long)q0 * 1536 + h * 64;  // Q[r][d], ld 1536
    const u16* Kg = qkv + qbase + 512 + h * 64;                   // K[s][d], ld 1536
    const u16* Vg = vt + (long long)z * 32768;                    // V^T[vd][s], ld 512

    const int t = threadIdx.x, lane = t & 63, wid = t >> 6;
    const int qd = lane >> 4, ml = lane & 15;
    const int wm = wid * 32;  // this wave's 32 Q-rows

    // Q fragments (A-layout: row=ml, k=qd*8+j), held for the whole kernel.
    half8 qf[2][2];
#pragma unroll
    for (int mt = 0; mt < 2; ++mt)
#pragma unroll
        for (int kf = 0; kf < 2; ++kf)
            qf[mt][kf] = *(const half8*)(Q + (long long)(wm + mt * 16 + ml) * 1536 + kf * 32 + qd * 8);

    f32x4 oacc[2][4] = {};
    float mrow[2][4], lrow[2][4];
#pragma unroll
    for (int mt = 0; mt < 2; ++mt)
#pragma unroll
        for (int r = 0; r < 4; ++r) { mrow[mt][r] = -3.0e38f; lrow[mt][r] = 0.f; }

    for (int kb = 0; kb < 4; ++kb) {
        // S = Q K^T for this 128-col block (B-layout: n=ml row of K, k=qd*8+j).
        f32x4 sacc[2][8] = {};
#pragma unroll
        for (int nt = 0; nt < 8; ++nt) {
#pragma unroll
            for (int kf = 0; kf < 2; ++kf) {
                half8 bf = *(const half8*)(Kg + (long long)(kb * 128 + nt * 16 + ml) * 1536 + kf * 32 + qd * 8);
#pragma unroll
                for (int mt = 0; mt < 2; ++mt)
                    sacc[mt][nt] = __builtin_amdgcn_mfma_f32_16x16x32_f16(qf[mt][kf], bf, sacc[mt][nt], 0, 0, 0);
            }
        }
        // scale + online softmax (rows live in (qd, r); cols spread over ml).
#pragma unroll
        for (int mt = 0; mt < 2; ++mt) {
#pragma unroll
            for (int r = 0; r < 4; ++r) {
                float mx = -3.0e38f;
#pragma unroll
                for (int nt = 0; nt < 8; ++nt) {
                    float s = sacc[mt][nt][r] * 0.125f;
                    sacc[mt][nt][r] = s;
                    mx = fmaxf(mx, s);
                }
#pragma unroll
                for (int o = 1; o < 16; o <<= 1) mx = fmaxf(mx, __shfl_xor(mx, o, 64));
                float mnew = fmaxf(mrow[mt][r], mx);
                float alpha = __expf(mrow[mt][r] - mnew);
                mrow[mt][r] = mnew;
                lrow[mt][r] *= alpha;
#pragma unroll
                for (int nt = 0; nt < 4; ++nt) oacc[mt][nt][r] *= alpha;
                float ps = 0.f;
#pragma unroll
                for (int nt = 0; nt < 8; ++nt) {
                    float p = __expf(sacc[mt][nt][r] - mnew);
                    sacc[mt][nt][r] = p;
                    ps += p;
                }
#pragma unroll
                for (int o = 1; o < 16; o <<= 1) ps += __shfl_xor(ps, o, 64);
                lrow[mt][r] += ps;
            }
        }
        // P -> LDS (each wave touches only its own 32-row slab: no barrier).
#pragma unroll
        for (int mt = 0; mt < 2; ++mt)
#pragma unroll
            for (int nt = 0; nt < 8; ++nt)
#pragma unroll
                for (int r = 0; r < 4; ++r)
                    Ps[(wm + mt * 16 + qd * 4 + r) * 136 + nt * 16 + ml] = f2h_bits(sacc[mt][nt][r]);
        // O += P V (A-frags of P read back from own slab; V^T frags from global).
#pragma unroll
        for (int kf = 0; kf < 4; ++kf) {
            half8 pf[2];
#pragma unroll
            for (int mt = 0; mt < 2; ++mt)
                pf[mt] = *(const half8*)(Ps + (wm + mt * 16 + ml) * 136 + kf * 32 + qd * 8);
#pragma unroll
            for (int nt = 0; nt < 4; ++nt) {
                half8 vf = *(const half8*)(Vg + (long long)(nt * 16 + ml) * 512 + kb * 128 + kf * 32 + qd * 8);
#pragma unroll
                for (int mt = 0; mt < 2; ++mt)
                    oacc[mt][nt] = __builtin_amdgcn_mfma_f32_16x16x32_f16(pf[mt], vf, oacc[mt][nt], 0, 0, 0);
            }
        }
    }

    // normalize and store: ob[(b*512 + s)*512 + h*64 + vd]
#pragma unroll
    for (int mt = 0; mt < 2; ++mt) {
#pragma unroll
        for (int r = 0; r < 4; ++r) {
            float inv = 1.f / lrow[mt][r];
            long long rowg = (long long)b * 512 + q0 + wm + mt * 16 + qd * 4 + r;
#pragma unroll
            for (int nt = 0; nt < 4; ++nt)
                ob[rowg * 512 + h * 64 + nt * 16 + ml] = f2h_bits(oacc[mt][nt][r] * inv);
        }
    }
}

template <int MODE>
__global__ void transpose_k(const void* __restrict__ src_, int s_ld, long long s_off,
                            long long s_so, long long s_si,
                            u16* __restrict__ dst, int d_ld, long long d_so, long long d_si,
                            int R, int Rs, int C, const void* caps)
{
    __shared__ u16 tile[32][33];
    const int z = blockIdx.z;
    const long long sb = s_off + (long long)(z >> 3) * s_so + (long long)(z & 7) * s_si;
    dst += (long long)(z >> 3) * d_so + (long long)(z & 7) * d_si;
    const int c0 = blockIdx.x * 32, r0 = blockIdx.y * 32;
    const int tx = threadIdx.x, ty = threadIdx.y;
    const int flag = (MODE == 1) ? detect_bf16(caps) : 0;
#pragma unroll
    for (int i = 0; i < 4; ++i) {
        int r = r0 + ty + i * 8, c = c0 + tx;
        if (r < R && c < C) {
            u16 v = 0;
            if (r < Rs) {
                size_t idx = (size_t)(sb + (long long)r * s_ld + c);
                if (MODE == 1) v = f2h_bits(ldin(src_, idx, flag));
                else           v = ((const u16*)src_)[idx];
            }
            tile[ty + i * 8][tx] = v;
        }
    }
    __syncthreads();
#pragma unroll
    for (int i = 0; i < 4; ++i) {
        int r = r0 + tx, c = c0 + ty + i * 8;
        if (r < R && c < C) dst[(long long)c * d_ld + r] = tile[tx][ty + i * 8];
    }
}

__global__ void qkvoT6_k(const void* Wq, const void* Wk, const void* Wv, const void* Wo,
                         u16* __restrict__ wqkvT6, u16* __restrict__ woT6,
                         const void* caps)
{
    __shared__ u16 tile[32][33];
    const int z = blockIdx.z;
    const int layer = z >> 2, sel = z & 3;
    const void* src = (sel == 0) ? Wq : (sel == 1) ? Wk : (sel == 2) ? Wv : Wo;
    u16* dst = (sel < 3) ? (wqkvT6 + (long long)layer * 786432 + (long long)sel * 262144)
                         : (woT6 + (long long)layer * 262144);
    const long long oW = (long long)layer * 262144;
    const int c0 = blockIdx.x * 32, r0 = blockIdx.y * 32;
    const int tx = threadIdx.x, ty = threadIdx.y;
    const int flag = detect_bf16(caps);
#pragma unroll
    for (int i = 0; i < 4; ++i) {
        int r = r0 + ty + i * 8, c = c0 + tx;
        tile[ty + i * 8][tx] = f2h_bits(ldin(src, (size_t)(oW + (long long)r * 512 + c), flag));
    }
    __syncthreads();
#pragma unroll
    for (int i = 0; i < 4; ++i) {
        int r = r0 + tx, c = c0 + ty + i * 8;
        dst[(long long)c * 512 + r] = tile[tx][ty + i * 8];
    }
}

__global__ void cvt_small_k(const void* srcW, const void* srcB, const void* candW, const void* candB,
                            const void* depW, const void* depB, const void* feasW, const void* feasB,
                            const void* pW, const void* pb, const void* boi, const void* b1i,
                            const void* b2i, const void* caps, float* __restrict__ dst)
{
    int i = blockIdx.x * 256 + threadIdx.x;
    if (i >= A_TOTAL) return;
    int flag = detect_bf16(caps);
    const void* s; int j;
    if      (i < A_SRCB)  { s = srcW;  j = i - A_SRCW; }
    else if (i < A_CANDW) { s = srcB;  j = i - A_SRCB; }
    else if (i < A_CANDB) { s = candW; j = i - A_CANDW; }
    else if (i < A_DEPW)  { s = candB; j = i - A_CANDB; }
    else if (i < A_DEPB)  { s = depW;  j = i - A_DEPW; }
    else if (i < A_FEASW) { s = depB;  j = i - A_DEPB; }
    else if (i < A_FEASB) { s = feasW; j = i - A_FEASW; }
    else if (i < A_PW)    { s = feasB; j = i - A_FEASB; }
    else if (i < A_PB)    { s = pW;    j = i - A_PW; }
    else if (i < A_BO)    { s = pb;    j = i - A_PB; }
    else if (i < A_B1)    { s = boi;   j = i - A_BO; }
    else if (i < A_B2)    { s = b1i;   j = i - A_B1; }
    else                  { s = b2i;   j = i - A_B2; }
    dst[i] = ldin(s, j, flag);
}

__global__ void catbias_k(const void* bq, const void* bk, const void* bv,
                          const void* caps, float* __restrict__ dst)
{
    int t = blockIdx.x * 256 + threadIdx.x;
    if (t >= 6 * 1536) return;
    int flag = detect_bf16(caps);
    int l = t / 1536, j = t - l * 1536;
    float v = (j < 512) ? ldin(bq, l * 512 + j, flag)
            : (j < 1024) ? ldin(bk, l * 512 + j - 512, flag)
                         : ldin(bv, l * 512 + j - 1024, flag);
    dst[t] = v;
}

__global__ __launch_bounds__(256) void gather_xin_k(
    const void* __restrict__ sol, const void* __restrict__ caps, const void* __restrict__ emb,
    u16* __restrict__ xin)
{
    const int row = blockIdx.x;
    const int b = row >> 9, s = row & 511;
    const int t = threadIdx.x;
    const int flag = detect_bf16(caps);
    float idxf = ldin(sol, (size_t)row * 4, flag);
    int idx = (int)(idxf + 0.5f);
    if (idx < 0) idx = 0;
    if (idx > 9999) idx = 9999;
    xin[(size_t)row * 288 + t] = f2h_bits(ldin(emb, (size_t)idx * 256 + t, flag));
    if (t < 32) {
        float v = 0.f;
        if (t == 0 && s != 0) {
            float rem = ldin(sol, ((size_t)b * 512) * 4 + 3, flag);
            float cap = ldin(caps, b, flag);
            float dem = ldin(sol, (size_t)row * 4 + 2, flag);
            v = 2.f * (dem - rem) / cap;
        }
        xin[(size_t)row * 288 + 256 + t] = f2h_bits(v);
    }
}

__global__ __launch_bounds__(256) void fixup_enc_k(
    const void* __restrict__ sol, const void* __restrict__ caps, const void* __restrict__ emb,
    const float* __restrict__ arena, float* __restrict__ xf, u16* __restrict__ xb)
{
    const int blk = blockIdx.x;
    const int b = blk & 7;
    const int s = (blk >> 3) ? 511 : 0;
    const int row = b * 512 + s;
    const int t = threadIdx.x;
    __shared__ float e[256];
    __shared__ float nds;
    const int flag = detect_bf16(caps);
    float idxf = ldin(sol, (size_t)row * 4, flag);
    int idx = (int)(idxf + 0.5f);
    if (idx < 0) idx = 0;
    if (idx > 9999) idx = 9999;
    e[t] = ldin(emb, (size_t)idx * 256 + t, flag);
    if (t == 0) {
        float rem = ldin(sol, ((size_t)b * 512) * 4 + 3, flag);
        float cap = ldin(caps, b, flag);
        float dem = ldin(sol, (size_t)row * 4 + 2, flag);
        nds = (s == 0) ? 0.f : 2.f * (dem - rem) / cap;
    }
    __syncthreads();
    const float* W  = (s == 0) ? arena + A_SRCW : arena + A_DEPW;
    const float* Bb = (s == 0) ? arena + A_SRCB : arena + A_DEPB;
    float a0 = 0.f, a1 = 0.f;
    for (int c = 0; c < 256; ++c) {
        float ev = e[c];
        a0 += ev * W[(size_t)c * 512 + t];
        a1 += ev * W[(size_t)c * 512 + t + 256];
    }
    float nd = nds;
    a0 += nd * W[256 * 512 + t] + Bb[t];
    a1 += nd * W[256 * 512 + t + 256] + Bb[t + 256];
    size_t o = (size_t)row * 512;
    xf[o + t] = a0;        xb[o + t] = f2h_bits(a0);
    xf[o + t + 256] = a1;  xb[o + t + 256] = f2h_bits(a1);
}

__global__ __launch_bounds__(256) void ffn2red_k(const float* __restrict__ tmp,
                                                 const float* __restrict__ bias,
                                                 float* __restrict__ xf, u16* __restrict__ xb)
{
    int i = blockIdx.x * 256 + threadIdx.x;
    float v = tmp[i] + tmp[i + 2097152] + bias[i & 511];
    float nv = xf[i] + v;
    xf[i] = nv;
    xb[i] = f2h_bits(nv);
}

__global__ __launch_bounds__(256) void feas_k(const float* __restrict__ xf,
                                              const float* __restrict__ arena,
                                              float* __restrict__ out)
{
    int w = blockIdx.x * 4 + (threadIdx.x >> 6);
    if (w >= 8 * 510) return;
    int lane = threadIdx.x & 63;
    int b = w / 510, j = w - b * 510;
    const float* xr = xf + ((size_t)(b * 512 + 1 + j)) * 512;
    const float* fW = arena + A_FEASW;
    float a = 0.f;
#pragma unroll
    for (int i = 0; i < 8; ++i) { int d = lane + 64 * i; a += xr[d] * fW[d]; }
#pragma unroll
    for (int o = 1; o < 64; o <<= 1) a += __shfl_xor(a, o, 64);
    if (lane == 0) out[8160 + b * 510 + j] = a + arena[A_FEASB];
}

__global__ __launch_bounds__(256) void ptr_k(const float* __restrict__ xf,
                                             const float* __restrict__ arena,
                                             float* __restrict__ out)
{
    int w = blockIdx.x * 4 + (threadIdx.x >> 6);
    if (w >= 8 * 510) return;
    int lane = threadIdx.x & 63;
    int b = w / 510, j = w - b * 510;
    const float* xr = xf + ((size_t)(b * 512 + 1 + j)) * 512;
    const float* pWa = arena + A_PW;
    float a0 = 0.f, a1 = 0.f;
#pragma unroll
    for (int i = 0; i < 8; ++i) {
        int d = lane + 64 * i;
        float x = xr[d];
        a0 += x * pWa[d * 2];
        a1 += x * pWa[d * 2 + 1];
    }
#pragma unroll
    for (int o = 1; o < 64; o <<= 1) { a0 += __shfl_xor(a0, o, 64); a1 += __shfl_xor(a1, o, 64); }
    if (lane == 0) {
        out[(size_t)b * 1020 + j]       = a0 + arena[A_PB];
        out[(size_t)b * 1020 + 510 + j] = a1 + arena[A_PB + 1];
    }
}

extern "C" void kernel_launch(void* const* d_in, const int* in_sizes, int n_in,
                              void* d_out, int out_size, void* d_ws, size_t ws_size,
                              hipStream_t stream)
{
    const void* sol   = d_in[0];
    const void* caps  = d_in[1];
    const void* emb   = d_in[2];
    const void* srcW  = d_in[3];
    const void* srcB  = d_in[4];
    const void* candW = d_in[5];
    const void* candB = d_in[6];
    const void* depW  = d_in[7];
    const void* depB  = d_in[8];
    const void* feasW = d_in[9];
    const void* feasB = d_in[10];
    const void* Wq  = d_in[11];
    const void* bq  = d_in[12];
    const void* Wk  = d_in[13];
    const void* bk  = d_in[14];
    const void* Wv  = d_in[15];
    const void* bv  = d_in[16];
    const void* Wo  = d_in[17];
    const void* boi = d_in[18];
    // d_in[19] = s_scale: softmax shift no-op
    const void* W1  = d_in[20];
    const void* b1i = d_in[21];
    const void* W2  = d_in[22];
    const void* b2i = d_in[23];
    const void* pW  = d_in[24];
    const void* pb  = d_in[25];
    float* out = (float*)d_out;

    // workspace (~86 MiB of 256 MiB)
    char* w = (char*)d_ws;
    float* xf    = (float*)w; w += 8388608;   // 4096x512 fp32 residual master
    u16* xb      = (u16*)w;   w += 4194304;   // 4096x512 fp16
    u16* qkvb    = (u16*)w;   w += 12582912;  // 4096x1536 fp16 (q|k|v)
    u16* vt      = (u16*)w;   w += 4194304;   // 64x64x512 fp16 (v^T per slice)
    u16* hb      = (u16*)w;   w += 16777216;  // 4096x2048 fp16 FFN hidden
    u16* xin     = hb;                        //  ALIAS: 4096x288 fp16 encoder input
    u16* encW    = hb + 4096 * 288;           //  ALIAS: 512x288 fp16 candW^T
    float* tmp2  = (float*)qkvb;              //  ALIAS: FFN2 split-K partials (qkvb+vt, 16 MB)
    u16* ob      = (u16*)w;   w += 4194304;   // 4096x512 fp16 attention out
    u16* wqkvT6  = (u16*)w;   w += 9437184;   // 6x 1536x512 fp16
    u16* woT6    = (u16*)w;   w += 3145728;   // 6x 512x512 fp16
    u16* w1T6    = (u16*)w;   w += 12582912;  // 6x 2048x512 fp16
    u16* w2T6    = (u16*)w;   w += 12582912;  // 6x 512x2048 fp16
    float* bqkvf = (float*)w; w += 36864;     // 6x1536 fp32
    float* arena = (float*)w; w += A_TOTAL * 4;

    dim3 tb(32, 8);
    cvt_small_k<<<dim3((A_TOTAL + 255) / 256), 256, 0, stream>>>(
        srcW, srcB, candW, candB, depW, depB, feasW, feasB, pW, pb, boi, b1i, b2i, caps, arena);
    catbias_k<<<dim3(36), 256, 0, stream>>>(bq, bk, bv, caps, bqkvf);

    // Weight transposes hoisted (3 dispatches).
    qkvoT6_k<<<dim3(16, 16, 24), tb, 0, stream>>>(Wq, Wk, Wv, Wo, wqkvT6, woT6, caps);
    transpose_k<1><<<dim3(64, 16, 6), tb, 0, stream>>>(W1, 2048, 0, 0, 1048576,
                                                       w1T6, 512, 0, 1048576, 512, 512, 2048, caps);
    transpose_k<1><<<dim3(16, 64, 6), tb, 0, stream>>>(W2, 512, 0, 0, 1048576,
                                                       w2T6, 2048, 0, 1048576, 2048, 2048, 512, caps);

    // Encoder via MFMA + 16-row fixup.
    gather_xin_k<<<dim3(4096), 256, 0, stream>>>(sol, caps, emb, xin);
    transpose_k<1><<<dim3(16, 9, 1), tb, 0, stream>>>(candW, 512, 0, 0, 0,
                                                      encW, 288, 0, 0, 288, 257, 512, caps);
    gemm_f16<2><<<dim3(4, 32, 1), 256, 0, stream>>>(
        xin, 288, 0, 0, encW, 288, 0, 0,
        xb, 512, 0, 0, arena + A_CANDB, xf, 1.f, 0, 512, 288);
    fixup_enc_k<<<dim3(16), 256, 0, stream>>>(sol, caps, emb, arena, xf, xb);

    for (int i = 0; i < 6; ++i) {
        gemm_f16<0><<<dim3(12, 32, 1), 256, 0, stream>>>(
            xb, 512, 0, 0, wqkvT6 + (long long)i * 786432, 512, 0, 0,
            qkvb, 1536, 0, 0, bqkvf + i * 1536, nullptr, 1.f, 0, 1536, 512);
        transpose_k<0><<<dim3(2, 16, 64), tb, 0, stream>>>(
            qkvb + 1024, 1536, 0, 786432, 64, vt, 512, 262144, 32768, 512, 512, 64, caps);

        // Fused attention: scores+softmax+PV in one dispatch, zero barriers.
        flash_k<<<dim3(4, 64), 256, 0, stream>>>(qkvb, vt, ob);

        gemm_f16<0><<<dim3(4, 32, 1), 256, 0, stream>>>(
            ob, 512, 0, 0, woT6 + (long long)i * 262144, 512, 0, 0,
            xb, 512, 0, 0, arena + A_BO + i * 512, xf, 1.f, 0, 512, 512);
        if (i == 0)
            feas_k<<<dim3(1020), 256, 0, stream>>>(xf, arena, out);
        gemm_f16<0><<<dim3(16, 32, 1), 256, 0, stream>>>(
            xb, 512, 0, 0, w1T6 + (long long)i * 1048576, 512, 0, 0,
            hb, 2048, 0, 0, arena + A_B1 + i * 2048, nullptr, 1.f, 1, 2048, 512);
        gemm_f16<1><<<dim3(4, 32, 2), 256, 0, stream>>>(
            hb, 2048, 0, 1024, w2T6 + (long long)i * 1048576, 2048, 0, 1024,
            tmp2, 512, 0, 2097152, nullptr, nullptr, 1.f, 0, 512, 1024);
        ffn2red_k<<<dim3(8192), 256, 0, stream>>>(tmp2, arena + A_B2 + i * 512, xf, xb);
    }
    ptr_k<<<dim3(1020), 256, 0, stream>>>(xf, arena, out);
}